// Round 2
// baseline (62225.104 us; speedup 1.0000x reference)
//
#include <hip/hip_runtime.h>
#include <hip/hip_cooperative_groups.h>
#include <math.h>

namespace cg = cooperative_groups;

#define L_SEQ 512
#define BATCH 16
#define D_IN  41
#define HD    800
#define G4    3200   // 4*H
#define A2H   1600   // 2*H
#define NA    20

// workspace layout (float offsets). Peak = 65,611,776 floats = 250.3 MiB.
// h2 aliases h1 (h1 is dead once gemm_pre1 has produced pre1).
#define OFF_A   ((size_t)0)                                   // pre dir-f: [512][16][3200]
#define OFF_B   (OFF_A + (size_t)L_SEQ * BATCH * G4)          // pre dir-b
#define OFF_H   (OFF_B + (size_t)L_SEQ * BATCH * G4)          // h1 / h2: [512][16][1600]
#define OFF_DIH (OFF_H + (size_t)L_SEQ * BATCH * A2H)         // [512][16][3]
#define OFF_HST (OFF_DIH + (size_t)L_SEQ * BATCH * 3)         // h state [2 dir][2 buf][800][16]

static __device__ __forceinline__ float sigf(float x) {
    return 1.0f / (1.0f + __expf(-x));
}

// ---------------------------------------------------------------------------
// K1: pre0[dir][t*16+b][g] = x[b][t][:41] . W_ih0[dir][g][:41] + b_ih + b_hh
// grid (13, 8192, 2), block 256
// ---------------------------------------------------------------------------
__global__ void pre0_kernel(const float* __restrict__ x,
                            const float* __restrict__ Wf, const float* __restrict__ bif,
                            const float* __restrict__ bhf,
                            const float* __restrict__ Wb, const float* __restrict__ bib,
                            const float* __restrict__ bhb,
                            float* __restrict__ outF, float* __restrict__ outB) {
    int g = blockIdx.x * 256 + threadIdx.x;
    if (g >= G4) return;
    int m = blockIdx.y;           // m = t*16 + b
    int dir = blockIdx.z;
    int b = m & 15, t = m >> 4;
    const float* W  = dir ? Wb  : Wf;
    const float* bi = dir ? bib : bif;
    const float* bh = dir ? bhb : bhf;
    float acc = bi[g] + bh[g];
    const float* xr = x + ((size_t)b * L_SEQ + t) * D_IN;   // x is [B][L][D]
    const float* wr = W + (size_t)g * D_IN;
    #pragma unroll
    for (int d = 0; d < D_IN; ++d) acc = fmaf(xr[d], wr[d], acc);
    (dir ? outB : outF)[(size_t)m * G4 + g] = acc;
}

// ---------------------------------------------------------------------------
// K2: cooperative bidirectional LSTM recurrence for one layer.
// grid 200 blocks x 256 threads: block = (dir = bid&1, wg = bid>>1), wg owns
// hidden slice j0 = wg*8 (8 hidden units x 4 gates = 32 gate rows).
// W_hh slice lives in VGPRs (w[4][25] per lane). Per step:
//   stage h_prev (global->LDS stride 17, conflict-free), register-tiled
//   partial GEMM (lane = (q=tid>>5, c=tid&31), k = c+32*kk), padded-LDS
//   transpose reduction over the 32 k-chunks, LSTM pointwise, h broadcast
//   via global + grid.sync().
// ---------------------------------------------------------------------------
__launch_bounds__(256, 1)
__global__ void recur_kernel(const float* __restrict__ preF, const float* __restrict__ preB,
                             const float* __restrict__ WhhF, const float* __restrict__ WhhB,
                             float* __restrict__ hout, float* __restrict__ hstate) {
    cg::grid_group grid = cg::this_grid();
    __shared__ float uni[13600];   // union: h stage (800*17) / reduce scratch (16*16*35)
    __shared__ float gates[512];   // [gate][jj][b]
    const int tid = threadIdx.x;
    const int dir = blockIdx.x & 1;
    const int wg  = blockIdx.x >> 1;          // 0..99
    const int j0  = wg * 8;
    const float* pre = dir ? preB : preF;     // [512*16][3200]
    const float* Whh = dir ? WhhB : WhhF;     // [3200][800]
    float* hstd = hstate + (size_t)dir * 2 * HD * BATCH;

    // zero both h-state double buffers (ws is poisoned each call)
    for (int i = blockIdx.x * 256 + tid; i < 2 * 2 * HD * BATCH; i += gridDim.x * 256)
        hstate[i] = 0.0f;

    // persistent W_hh slice in registers
    const int q = tid >> 5, c = tid & 31;
    float w[4][25];
    #pragma unroll
    for (int gi = 0; gi < 4; ++gi) {
        int rl = q * 4 + gi;                           // 0..31
        int row = (rl >> 3) * HD + j0 + (rl & 7);      // gate*800 + j
        const float* wr = Whh + (size_t)row * HD + c;
        #pragma unroll
        for (int kk = 0; kk < 25; ++kk) w[gi][kk] = wr[kk * 32];
    }
    float cstate = 0.0f;                 // lanes < 128: c for (jj=tid>>4, b=tid&15)
    const int r2p = tid & 15, bp = tid >> 4;

    grid.sync();

    for (int it = 0; it < L_SEQ; ++it) {
        const int t = dir ? (L_SEQ - 1 - it) : it;

        // prefetch this lane's two pre-activation values (latency hidden by GEMM)
        float pv[2];
        #pragma unroll
        for (int hh = 0; hh < 2; ++hh) {
            int rl = (r2p >> 1) * 4 + (r2p & 1) + 2 * hh;
            int row = (rl >> 3) * HD + j0 + (rl & 7);
            pv[hh] = pre[((size_t)t * BATCH + bp) * G4 + row];
        }

        // stage h_prev into LDS, layout [k][b] stride 17 (conflict-free reads)
        const float* hsrc = hstd + ((it & 1) ^ 1) * (HD * BATCH);
        for (int e = tid; e < HD * BATCH; e += 256)
            uni[(e >> 4) * 17 + (e & 15)] = hsrc[e];
        __syncthreads();

        // phase A: acc[gi][b] += w[gi][kk] * h[b][c+32kk]
        float acc[4][16];
        #pragma unroll
        for (int gi = 0; gi < 4; ++gi)
            #pragma unroll
            for (int b = 0; b < 16; ++b) acc[gi][b] = 0.0f;
        #pragma unroll
        for (int kk = 0; kk < 25; ++kk) {
            const int kb = (c + kk * 32) * 17;
            float hreg[16];
            #pragma unroll
            for (int b = 0; b < 16; ++b) hreg[b] = uni[kb + b];
            #pragma unroll
            for (int gi = 0; gi < 4; ++gi)
                #pragma unroll
                for (int b = 0; b < 16; ++b)
                    acc[gi][b] = fmaf(w[gi][kk], hreg[b], acc[gi][b]);
        }
        __syncthreads();   // h consumed; reuse uni as reduce scratch

        // phase B: reduce over 32 k-chunks, two halves (gi pairs) to fit LDS
        #pragma unroll
        for (int half = 0; half < 2; ++half) {
            #pragma unroll
            for (int u = 0; u < 2; ++u) {
                const int r2w = q * 2 + u;
                #pragma unroll
                for (int b = 0; b < 16; ++b)
                    uni[(b * 16 + r2w) * 35 + c] = acc[2 * half + u][b];
            }
            __syncthreads();
            {
                float s = pv[half];
                const int base = (bp * 16 + r2p) * 35;
                #pragma unroll
                for (int cc = 0; cc < 32; ++cc) s += uni[base + cc];
                int rl = (r2p >> 1) * 4 + (r2p & 1) + 2 * half;
                int gate = rl >> 3, jj = rl & 7;
                gates[gate * 128 + jj * 16 + bp] = s;
            }
            __syncthreads();
        }

        // pointwise LSTM update; write h to state buffer + layer output
        if (tid < 128) {
            const int jj = tid >> 4, b = tid & 15;
            float ig = gates[0 * 128 + jj * 16 + b];
            float fg = gates[1 * 128 + jj * 16 + b];
            float gg = gates[2 * 128 + jj * 16 + b];
            float og = gates[3 * 128 + jj * 16 + b];
            float cn = sigf(fg) * cstate + sigf(ig) * tanhf(gg);
            cstate = cn;
            float hn = sigf(og) * tanhf(cn);
            hstd[(it & 1) * (HD * BATCH) + (j0 + jj) * 16 + b] = hn;
            hout[((size_t)t * BATCH + b) * A2H + dir * HD + j0 + jj] = hn;
        }
        __threadfence();
        grid.sync();
    }
}

// ---------------------------------------------------------------------------
// K3: pre1[dir][m][n] = h1[m][:1600] . W_ih1[dir][n][:1600] + b_ih + b_hh
// 128x128 tile, 256 threads, 8x8 micro-tile, BK=16. grid (25, 64, 2).
// ---------------------------------------------------------------------------
__launch_bounds__(256)
__global__ void gemm_pre1_kernel(const float* __restrict__ Ah,
                                 const float* __restrict__ WF, const float* __restrict__ biF,
                                 const float* __restrict__ bhF,
                                 const float* __restrict__ WB, const float* __restrict__ biB,
                                 const float* __restrict__ bhB,
                                 float* __restrict__ CF, float* __restrict__ CB) {
    __shared__ float As[16][132];
    __shared__ float Bs[16][132];
    const int dir = blockIdx.z;
    const float* Bw = dir ? WB : WF;
    const float* bi = dir ? biB : biF;
    const float* bh = dir ? bhB : bhF;
    float* C = dir ? CB : CF;
    const int n0 = blockIdx.x * 128;
    const int m0 = blockIdx.y * 128;
    const int tid = threadIdx.x;
    const int mt = tid >> 4, nt = tid & 15;
    const int r = tid >> 2, kq = tid & 3;

    float acc[8][8];
    #pragma unroll
    for (int i = 0; i < 8; ++i)
        #pragma unroll
        for (int j = 0; j < 8; ++j) acc[i][j] = 0.0f;

    for (int k0 = 0; k0 < A2H; k0 += 16) {
        float4 a0 = *(const float4*)(Ah + (size_t)(m0 + r) * A2H + k0 + kq * 4);
        float4 a1 = *(const float4*)(Ah + (size_t)(m0 + r + 64) * A2H + k0 + kq * 4);
        float4 b0 = *(const float4*)(Bw + (size_t)(n0 + r) * A2H + k0 + kq * 4);
        float4 b1 = *(const float4*)(Bw + (size_t)(n0 + r + 64) * A2H + k0 + kq * 4);
        __syncthreads();
        As[kq * 4 + 0][r] = a0.x;  As[kq * 4 + 1][r] = a0.y;
        As[kq * 4 + 2][r] = a0.z;  As[kq * 4 + 3][r] = a0.w;
        As[kq * 4 + 0][r + 64] = a1.x;  As[kq * 4 + 1][r + 64] = a1.y;
        As[kq * 4 + 2][r + 64] = a1.z;  As[kq * 4 + 3][r + 64] = a1.w;
        Bs[kq * 4 + 0][r] = b0.x;  Bs[kq * 4 + 1][r] = b0.y;
        Bs[kq * 4 + 2][r] = b0.z;  Bs[kq * 4 + 3][r] = b0.w;
        Bs[kq * 4 + 0][r + 64] = b1.x;  Bs[kq * 4 + 1][r + 64] = b1.y;
        Bs[kq * 4 + 2][r + 64] = b1.z;  Bs[kq * 4 + 3][r + 64] = b1.w;
        __syncthreads();
        #pragma unroll
        for (int kk = 0; kk < 16; ++kk) {
            float av[8], bv[8];
            #pragma unroll
            for (int j = 0; j < 8; ++j) av[j] = As[kk][mt * 8 + j];
            #pragma unroll
            for (int j = 0; j < 8; ++j) bv[j] = Bs[kk][nt * 8 + j];
            #pragma unroll
            for (int i = 0; i < 8; ++i)
                #pragma unroll
                for (int j = 0; j < 8; ++j)
                    acc[i][j] = fmaf(av[i], bv[j], acc[i][j]);
        }
    }
    float bias[8];
    #pragma unroll
    for (int j = 0; j < 8; ++j) { int n = n0 + nt * 8 + j; bias[j] = bi[n] + bh[n]; }
    #pragma unroll
    for (int i = 0; i < 8; ++i) {
        size_t base = (size_t)(m0 + mt * 8 + i) * G4 + n0 + nt * 8;
        #pragma unroll
        for (int j = 0; j < 8; ++j) C[base + j] = acc[i][j] + bias[j];
    }
}

// ---------------------------------------------------------------------------
// K4: linear head + softmax over BATCH dim (faithful nn.Softmax(dim=1)) +
// dihedrals. One block per t, 320 threads (= 16 b x 20 a).
// ---------------------------------------------------------------------------
__global__ void head_kernel(const float* __restrict__ out2,   // [8192][1600]
                            const float* __restrict__ Wlin,   // [20][1600]
                            const float* __restrict__ blin,   // [20]
                            const float* __restrict__ alphabet, // [20][3]
                            float* __restrict__ dih) {        // [512][16][3]
    __shared__ float lg[16][21];
    __shared__ float sal[20][3], cal[20][3];
    const int t = blockIdx.x;
    const int tid = threadIdx.x;
    if (tid < 60) {
        int a = tid / 3, d = tid - 3 * (tid / 3);
        float v = alphabet[a * 3 + d];
        sal[a][d] = sinf(v);
        cal[a][d] = cosf(v);
    }
    const int b = tid / 20, a = tid - 20 * (tid / 20);
    const float* orow = out2 + ((size_t)t * BATCH + b) * A2H;
    const float* wrow = Wlin + (size_t)a * A2H;
    float s = blin[a];
    for (int k = 0; k < A2H; k += 4) {
        float4 ov = *(const float4*)(orow + k);
        float4 wv = *(const float4*)(wrow + k);
        s = fmaf(ov.x, wv.x, s);
        s = fmaf(ov.y, wv.y, s);
        s = fmaf(ov.z, wv.z, s);
        s = fmaf(ov.w, wv.w, s);
    }
    lg[b][a] = s;
    __syncthreads();
    if (tid < NA) {   // softmax over b for column a = tid
        float mx = -1e30f;
        #pragma unroll
        for (int bb = 0; bb < BATCH; ++bb) mx = fmaxf(mx, lg[bb][tid]);
        float sum = 0.0f;
        #pragma unroll
        for (int bb = 0; bb < BATCH; ++bb) {
            float e = expf(lg[bb][tid] - mx);
            lg[bb][tid] = e;
            sum += e;
        }
        float inv = 1.0f / sum;
        #pragma unroll
        for (int bb = 0; bb < BATCH; ++bb) lg[bb][tid] *= inv;
    }
    __syncthreads();
    if (tid < 48) {
        int bb = tid / 3, dd = tid - 3 * (tid / 3);
        float ss = 0.0f, cc = 0.0f;
        #pragma unroll
        for (int aa = 0; aa < NA; ++aa) {
            float p = lg[bb][aa];
            ss = fmaf(p, sal[aa][dd], ss);
            cc = fmaf(p, cal[aa][dd], cc);
        }
        dih[((size_t)t * BATCH + bb) * 3 + dd] = atan2f(ss, cc);
    }
}

// ---------------------------------------------------------------------------
// K5: sequential NeRF chain. 1 block, lane b < 16 walks its batch serially.
// ---------------------------------------------------------------------------
__global__ void nerf_kernel(const float* __restrict__ dih, float* __restrict__ out) {
    const int b = threadIdx.x;
    if (b >= BATCH) return;
    const float BL0 = 145.801f, BL1 = 152.326f, BL2 = 132.868f;
    const float BA0 = 2.124f,   BA1 = 1.941f,   BA2 = 2.028f;
    const float rr[3] = {BL0, BL1, BL2};
    const float st3[3] = {sinf(BA0), sinf(BA1), sinf(BA2)};
    const float ct3[3] = {cosf(BA0), cosf(BA1), cosf(BA2)};
    float ax = 0.f, ay = 0.f, az = 0.f;
    float bx = BL0, by = 0.f, bz = 0.f;
    float ang = 3.14159265358979323846f - BA0;
    float cx = bx + BL1 * cosf(ang), cy = BL1 * sinf(ang), cz = 0.f;
    for (int l = 0; l < L_SEQ; ++l) {
        #pragma unroll
        for (int d = 0; d < 3; ++d) {
            const int s = l * 3 + d;
            const float r = rr[d], st = st3[d], ct = ct3[d];
            float ph = dih[((size_t)l * BATCH + b) * 3 + d];
            float sp, cp;
            __sincosf(ph, &sp, &cp);
            float d2x = -r * ct, d2y = r * st * cp, d2z = r * st * sp;
            // bc = normalize(c - b)
            float bcx = cx - bx, bcy = cy - by, bcz = cz - bz;
            float inv = 1.0f / (sqrtf(bcx * bcx + bcy * bcy + bcz * bcz) + 1e-8f);
            bcx *= inv; bcy *= inv; bcz *= inv;
            // n = normalize(cross(b - a, bc))
            float abx = bx - ax, aby = by - ay, abz = bz - az;
            float nx = aby * bcz - abz * bcy;
            float ny = abz * bcx - abx * bcz;
            float nz = abx * bcy - aby * bcx;
            inv = 1.0f / (sqrtf(nx * nx + ny * ny + nz * nz) + 1e-8f);
            nx *= inv; ny *= inv; nz *= inv;
            // m1 = cross(n, bc)
            float m1x = ny * bcz - nz * bcy;
            float m1y = nz * bcx - nx * bcz;
            float m1z = nx * bcy - ny * bcx;
            float dx = bcx * d2x + m1x * d2y + nx * d2z + cx;
            float dy = bcy * d2x + m1y * d2y + ny * d2z + cy;
            float dz = bcz * d2x + m1z * d2y + nz * d2z + cz;
            size_t o = ((size_t)s * BATCH + b) * 3;
            out[o + 0] = dx; out[o + 1] = dy; out[o + 2] = dz;
            ax = bx; ay = by; az = bz;
            bx = cx; by = cy; bz = cz;
            cx = dx; cy = dy; cz = dz;
        }
    }
}

// ---------------------------------------------------------------------------
extern "C" void kernel_launch(void* const* d_in, const int* in_sizes, int n_in,
                              void* d_out, int out_size, void* d_ws, size_t ws_size,
                              hipStream_t stream) {
    (void)in_sizes; (void)n_in; (void)out_size; (void)ws_size;
    const float* x        = (const float*)d_in[0];
    const float* W_ih_l0f = (const float*)d_in[1];
    const float* W_hh_l0f = (const float*)d_in[2];
    const float* b_ih_l0f = (const float*)d_in[3];
    const float* b_hh_l0f = (const float*)d_in[4];
    const float* W_ih_l0b = (const float*)d_in[5];
    const float* W_hh_l0b = (const float*)d_in[6];
    const float* b_ih_l0b = (const float*)d_in[7];
    const float* b_hh_l0b = (const float*)d_in[8];
    const float* W_ih_l1f = (const float*)d_in[9];
    const float* W_hh_l1f = (const float*)d_in[10];
    const float* b_ih_l1f = (const float*)d_in[11];
    const float* b_hh_l1f = (const float*)d_in[12];
    const float* W_ih_l1b = (const float*)d_in[13];
    const float* W_hh_l1b = (const float*)d_in[14];
    const float* b_ih_l1b = (const float*)d_in[15];
    const float* b_hh_l1b = (const float*)d_in[16];
    const float* W_lin    = (const float*)d_in[17];
    const float* b_lin    = (const float*)d_in[18];
    const float* alphabet = (const float*)d_in[19];

    float* ws  = (float*)d_ws;
    float* bufA = ws + OFF_A;
    float* bufB = ws + OFF_B;
    float* h12  = ws + OFF_H;    // h1, then reused as h2
    float* dih  = ws + OFF_DIH;
    float* hst  = ws + OFF_HST;

    // 1. layer-0 pre-activations (both dirs)
    hipLaunchKernelGGL(pre0_kernel, dim3(13, L_SEQ * BATCH, 2), dim3(256), 0, stream,
                       x, W_ih_l0f, b_ih_l0f, b_hh_l0f,
                       W_ih_l0b, b_ih_l0b, b_hh_l0b, bufA, bufB);

    // 2. layer-0 recurrence (cooperative, fwd+bwd concurrently) -> h1
    {
        const float* a0 = bufA; const float* a1 = bufB;
        const float* a2 = W_hh_l0f; const float* a3 = W_hh_l0b;
        float* a4 = h12; float* a5 = hst;
        void* args[] = {&a0, &a1, &a2, &a3, &a4, &a5};
        hipLaunchCooperativeKernel((const void*)recur_kernel, dim3(200), dim3(256),
                                   args, 0, stream);
    }

    // 3. layer-1 pre-activations: big fp32 GEMM, overwrites bufA/bufB
    hipLaunchKernelGGL(gemm_pre1_kernel, dim3(G4 / 128, (L_SEQ * BATCH) / 128, 2),
                       dim3(256), 0, stream,
                       h12, W_ih_l1f, b_ih_l1f, b_hh_l1f,
                       W_ih_l1b, b_ih_l1b, b_hh_l1b, bufA, bufB);

    // 4. layer-1 recurrence -> h2 (aliases h1; h1 consumed by step 3)
    {
        const float* a0 = bufA; const float* a1 = bufB;
        const float* a2 = W_hh_l1f; const float* a3 = W_hh_l1b;
        float* a4 = h12; float* a5 = hst;
        void* args[] = {&a0, &a1, &a2, &a3, &a4, &a5};
        hipLaunchCooperativeKernel((const void*)recur_kernel, dim3(200), dim3(256),
                                   args, 0, stream);
    }

    // 5. head: linear + softmax(dim=batch) + dihedrals
    hipLaunchKernelGGL(head_kernel, dim3(L_SEQ), dim3(320), 0, stream,
                       h12, W_lin, b_lin, alphabet, dih);

    // 6. sequential NeRF extension
    hipLaunchKernelGGL(nerf_kernel, dim3(1), dim3(64), 0, stream,
                       dih, (float*)d_out);
}

// Round 3
// 28763.138 us; speedup vs baseline: 2.1634x; 2.1634x over previous
//
#include <hip/hip_runtime.h>
#include <math.h>

#define L_SEQ 512
#define BATCH 16
#define D_IN  41
#define HD    800
#define G4    3200   // 4*H
#define A2H   1600   // 2*H
#define NA    20

// workspace layout (float offsets). Peak ~250.4 MiB.
#define OFF_A   ((size_t)0)                                   // pre dir-f: [512][16][3200]
#define OFF_B   (OFF_A + (size_t)L_SEQ * BATCH * G4)          // pre dir-b
#define OFF_H   (OFF_B + (size_t)L_SEQ * BATCH * G4)          // h1 / h2: [512][16][1600]
#define OFF_DIH (OFF_H + (size_t)L_SEQ * BATCH * A2H)         // [512][16][3]
#define OFF_HST (OFF_DIH + (size_t)L_SEQ * BATCH * 3)         // h state [2 dir][2 buf][800][16]
#define OFF_BAR (OFF_HST + (size_t)2 * 2 * HD * BATCH)        // barrier: 128 ints

static __device__ __forceinline__ float sigf(float x) {
    return 1.0f / (1.0f + __expf(-x));
}

// ---------------------------------------------------------------------------
// Hand-rolled device-scope barrier (per direction, 100 blocks each).
// cnt/gen live in d_ws on separate 128B lines. Master (last arriver) resets
// cnt (relaxed) then bumps gen (release); spinners acquire gen. RMW release
// sequences make every block's prior stores visible after the barrier.
// ---------------------------------------------------------------------------
static __device__ __forceinline__ void dbar(int* cnt, int* gen, int nblk) {
    __syncthreads();
    if (threadIdx.x == 0) {
        int g = __hip_atomic_load(gen, __ATOMIC_RELAXED, __HIP_MEMORY_SCOPE_AGENT);
        int v = __hip_atomic_fetch_add(cnt, 1, __ATOMIC_ACQ_REL, __HIP_MEMORY_SCOPE_AGENT);
        if (v == nblk - 1) {
            __hip_atomic_store(cnt, 0, __ATOMIC_RELAXED, __HIP_MEMORY_SCOPE_AGENT);
            __hip_atomic_store(gen, g + 1, __ATOMIC_RELEASE, __HIP_MEMORY_SCOPE_AGENT);
        } else {
            while (__hip_atomic_load(gen, __ATOMIC_ACQUIRE, __HIP_MEMORY_SCOPE_AGENT) == g)
                __builtin_amdgcn_s_sleep(2);
        }
    }
    __syncthreads();
}

__global__ void init_bar_kernel(int* bar) {
    bar[threadIdx.x] = 0;   // 128 ints: cnt0@0, gen0@32, cnt1@64, gen1@96
}

// ---------------------------------------------------------------------------
// K1: pre0[dir][t*16+b][g] = x[b][t][:41] . W_ih0[dir][g][:41] + b_ih + b_hh
// ---------------------------------------------------------------------------
__global__ void pre0_kernel(const float* __restrict__ x,
                            const float* __restrict__ Wf, const float* __restrict__ bif,
                            const float* __restrict__ bhf,
                            const float* __restrict__ Wb, const float* __restrict__ bib,
                            const float* __restrict__ bhb,
                            float* __restrict__ outF, float* __restrict__ outB) {
    int g = blockIdx.x * 256 + threadIdx.x;
    if (g >= G4) return;
    int m = blockIdx.y;           // m = t*16 + b
    int dir = blockIdx.z;
    int b = m & 15, t = m >> 4;
    const float* W  = dir ? Wb  : Wf;
    const float* bi = dir ? bib : bif;
    const float* bh = dir ? bhb : bhf;
    float acc = bi[g] + bh[g];
    const float* xr = x + ((size_t)b * L_SEQ + t) * D_IN;   // x is [B][L][D]
    const float* wr = W + (size_t)g * D_IN;
    #pragma unroll
    for (int d = 0; d < D_IN; ++d) acc = fmaf(xr[d], wr[d], acc);
    (dir ? outB : outF)[(size_t)m * G4 + g] = acc;
}

// ---------------------------------------------------------------------------
// K2: bidirectional LSTM recurrence, custom per-direction barrier.
// 200 blocks x 256 threads (co-resident via cooperative launch): block =
// (dir = bid&1, wg = bid>>1); wg owns 8 hidden units (32 gate rows), W_hh
// slice persistent in VGPRs (w[4][25]/lane).
// ---------------------------------------------------------------------------
__launch_bounds__(256, 1)
__global__ void recur_kernel(const float* __restrict__ preF, const float* __restrict__ preB,
                             const float* __restrict__ WhhF, const float* __restrict__ WhhB,
                             float* __restrict__ hout, float* __restrict__ hstate,
                             int* __restrict__ bar) {
    __shared__ float uni[13600];   // union: h stage (800*17) / reduce scratch (16*16*35)
    __shared__ float gates[512];   // [gate][jj][b]
    const int tid = threadIdx.x;
    const int dir = blockIdx.x & 1;
    const int wg  = blockIdx.x >> 1;          // 0..99
    const int j0  = wg * 8;
    const float* pre = dir ? preB : preF;     // [512*16][3200]
    const float* Whh = dir ? WhhB : WhhF;     // [3200][800]
    float* hstd = hstate + (size_t)dir * 2 * HD * BATCH;
    int* cnt = bar + dir * 64;
    int* gen = bar + dir * 64 + 32;
    const int NBLK = 100;

    // zero this direction's h-state double buffers (ws is poisoned each call)
    for (int i = (blockIdx.x >> 1) * 256 + tid; i < 2 * HD * BATCH; i += 100 * 256)
        hstd[i] = 0.0f;

    // persistent W_hh slice in registers
    const int q = tid >> 5, c = tid & 31;
    float w[4][25];
    #pragma unroll
    for (int gi = 0; gi < 4; ++gi) {
        int rl = q * 4 + gi;                           // 0..31
        int row = (rl >> 3) * HD + j0 + (rl & 7);      // gate*800 + j
        const float* wr = Whh + (size_t)row * HD + c;
        #pragma unroll
        for (int kk = 0; kk < 25; ++kk) w[gi][kk] = wr[kk * 32];
    }
    float cstate = 0.0f;                 // lanes < 128: c for (jj=tid>>4, b=tid&15)
    const int r2p = tid & 15, bp = tid >> 4;

    dbar(cnt, gen, NBLK);   // h-state zeroing visible to all blocks of this dir

    for (int it = 0; it < L_SEQ; ++it) {
        const int t = dir ? (L_SEQ - 1 - it) : it;

        // prefetch this lane's two pre-activation values (latency hidden)
        float pv[2];
        #pragma unroll
        for (int hh = 0; hh < 2; ++hh) {
            int rl = (r2p >> 1) * 4 + (r2p & 1) + 2 * hh;
            int row = (rl >> 3) * HD + j0 + (rl & 7);
            pv[hh] = pre[((size_t)t * BATCH + bp) * G4 + row];
        }

        // stage h_prev into LDS (float4 global reads), layout [k][b] stride 17
        const float* hsrc = hstd + ((it & 1) ^ 1) * (HD * BATCH);
        #pragma unroll
        for (int i = 0; i < 13; ++i) {
            int e = tid * 4 + i * 1024;
            if (e < HD * BATCH) {
                float4 hv = *(const float4*)(hsrc + e);
                int k = e >> 4, b = e & 15;
                uni[k * 17 + b + 0] = hv.x;
                uni[k * 17 + b + 1] = hv.y;
                uni[k * 17 + b + 2] = hv.z;
                uni[k * 17 + b + 3] = hv.w;
            }
        }
        __syncthreads();

        // phase A: acc[gi][b] += w[gi][kk] * h[b][c+32kk]
        float acc[4][16];
        #pragma unroll
        for (int gi = 0; gi < 4; ++gi)
            #pragma unroll
            for (int b = 0; b < 16; ++b) acc[gi][b] = 0.0f;
        #pragma unroll
        for (int kk = 0; kk < 25; ++kk) {
            const int kb = (c + kk * 32) * 17;
            float hreg[16];
            #pragma unroll
            for (int b = 0; b < 16; ++b) hreg[b] = uni[kb + b];
            #pragma unroll
            for (int gi = 0; gi < 4; ++gi)
                #pragma unroll
                for (int b = 0; b < 16; ++b)
                    acc[gi][b] = fmaf(w[gi][kk], hreg[b], acc[gi][b]);
        }
        __syncthreads();   // h consumed; reuse uni as reduce scratch

        // phase B: reduce over the 32 k-chunks, two halves to fit LDS
        #pragma unroll
        for (int half = 0; half < 2; ++half) {
            #pragma unroll
            for (int u = 0; u < 2; ++u) {
                const int r2w = q * 2 + u;
                #pragma unroll
                for (int b = 0; b < 16; ++b)
                    uni[(b * 16 + r2w) * 35 + c] = acc[2 * half + u][b];
            }
            __syncthreads();
            {
                float s = pv[half];
                const int base = (bp * 16 + r2p) * 35;
                #pragma unroll
                for (int cc = 0; cc < 32; ++cc) s += uni[base + cc];
                int rl = (r2p >> 1) * 4 + (r2p & 1) + 2 * half;
                int gate = rl >> 3, jj = rl & 7;
                gates[gate * 128 + jj * 16 + bp] = s;
            }
            __syncthreads();
        }

        // pointwise LSTM update; write h to state buffer + layer output
        if (tid < 128) {
            const int jj = tid >> 4, b = tid & 15;
            float ig = gates[0 * 128 + jj * 16 + b];
            float fg = gates[1 * 128 + jj * 16 + b];
            float gg = gates[2 * 128 + jj * 16 + b];
            float og = gates[3 * 128 + jj * 16 + b];
            float cn = sigf(fg) * cstate + sigf(ig) * tanhf(gg);
            cstate = cn;
            float hn = sigf(og) * tanhf(cn);
            hstd[(it & 1) * (HD * BATCH) + (j0 + jj) * 16 + b] = hn;
            hout[((size_t)t * BATCH + b) * A2H + dir * HD + j0 + jj] = hn;
        }
        dbar(cnt, gen, NBLK);
    }
}

// ---------------------------------------------------------------------------
// K3: pre1[dir][m][n] = h1[m][:1600] . W_ih1[dir][n][:1600] + b_ih + b_hh
// 128x128 tile, 256 threads, 8x8 micro-tile, BK=16. grid (25, 64, 2).
// ---------------------------------------------------------------------------
__launch_bounds__(256)
__global__ void gemm_pre1_kernel(const float* __restrict__ Ah,
                                 const float* __restrict__ WF, const float* __restrict__ biF,
                                 const float* __restrict__ bhF,
                                 const float* __restrict__ WB, const float* __restrict__ biB,
                                 const float* __restrict__ bhB,
                                 float* __restrict__ CF, float* __restrict__ CB) {
    __shared__ float As[16][132];
    __shared__ float Bs[16][132];
    const int dir = blockIdx.z;
    const float* Bw = dir ? WB : WF;
    const float* bi = dir ? biB : biF;
    const float* bh = dir ? bhB : bhF;
    float* C = dir ? CB : CF;
    const int n0 = blockIdx.x * 128;
    const int m0 = blockIdx.y * 128;
    const int tid = threadIdx.x;
    const int mt = tid >> 4, nt = tid & 15;
    const int r = tid >> 2, kq = tid & 3;

    float acc[8][8];
    #pragma unroll
    for (int i = 0; i < 8; ++i)
        #pragma unroll
        for (int j = 0; j < 8; ++j) acc[i][j] = 0.0f;

    for (int k0 = 0; k0 < A2H; k0 += 16) {
        float4 a0 = *(const float4*)(Ah + (size_t)(m0 + r) * A2H + k0 + kq * 4);
        float4 a1 = *(const float4*)(Ah + (size_t)(m0 + r + 64) * A2H + k0 + kq * 4);
        float4 b0 = *(const float4*)(Bw + (size_t)(n0 + r) * A2H + k0 + kq * 4);
        float4 b1 = *(const float4*)(Bw + (size_t)(n0 + r + 64) * A2H + k0 + kq * 4);
        __syncthreads();
        As[kq * 4 + 0][r] = a0.x;  As[kq * 4 + 1][r] = a0.y;
        As[kq * 4 + 2][r] = a0.z;  As[kq * 4 + 3][r] = a0.w;
        As[kq * 4 + 0][r + 64] = a1.x;  As[kq * 4 + 1][r + 64] = a1.y;
        As[kq * 4 + 2][r + 64] = a1.z;  As[kq * 4 + 3][r + 64] = a1.w;
        Bs[kq * 4 + 0][r] = b0.x;  Bs[kq * 4 + 1][r] = b0.y;
        Bs[kq * 4 + 2][r] = b0.z;  Bs[kq * 4 + 3][r] = b0.w;
        Bs[kq * 4 + 0][r + 64] = b1.x;  Bs[kq * 4 + 1][r + 64] = b1.y;
        Bs[kq * 4 + 2][r + 64] = b1.z;  Bs[kq * 4 + 3][r + 64] = b1.w;
        __syncthreads();
        #pragma unroll
        for (int kk = 0; kk < 16; ++kk) {
            float av[8], bv[8];
            #pragma unroll
            for (int j = 0; j < 8; ++j) av[j] = As[kk][mt * 8 + j];
            #pragma unroll
            for (int j = 0; j < 8; ++j) bv[j] = Bs[kk][nt * 8 + j];
            #pragma unroll
            for (int i = 0; i < 8; ++i)
                #pragma unroll
                for (int j = 0; j < 8; ++j)
                    acc[i][j] = fmaf(av[i], bv[j], acc[i][j]);
        }
    }
    float bias[8];
    #pragma unroll
    for (int j = 0; j < 8; ++j) { int n = n0 + nt * 8 + j; bias[j] = bi[n] + bh[n]; }
    #pragma unroll
    for (int i = 0; i < 8; ++i) {
        size_t base = (size_t)(m0 + mt * 8 + i) * G4 + n0 + nt * 8;
        #pragma unroll
        for (int j = 0; j < 8; ++j) C[base + j] = acc[i][j] + bias[j];
    }
}

// ---------------------------------------------------------------------------
// K4: linear head + softmax over BATCH dim + dihedrals. One block per t.
// ---------------------------------------------------------------------------
__global__ void head_kernel(const float* __restrict__ out2,   // [8192][1600]
                            const float* __restrict__ Wlin,   // [20][1600]
                            const float* __restrict__ blin,   // [20]
                            const float* __restrict__ alphabet, // [20][3]
                            float* __restrict__ dih) {        // [512][16][3]
    __shared__ float lg[16][21];
    __shared__ float sal[20][3], cal[20][3];
    const int t = blockIdx.x;
    const int tid = threadIdx.x;
    if (tid < 60) {
        int a = tid / 3, d = tid - 3 * (tid / 3);
        float v = alphabet[a * 3 + d];
        sal[a][d] = sinf(v);
        cal[a][d] = cosf(v);
    }
    const int b = tid / 20, a = tid - 20 * (tid / 20);
    const float* orow = out2 + ((size_t)t * BATCH + b) * A2H;
    const float* wrow = Wlin + (size_t)a * A2H;
    float s = blin[a];
    for (int k = 0; k < A2H; k += 4) {
        float4 ov = *(const float4*)(orow + k);
        float4 wv = *(const float4*)(wrow + k);
        s = fmaf(ov.x, wv.x, s);
        s = fmaf(ov.y, wv.y, s);
        s = fmaf(ov.z, wv.z, s);
        s = fmaf(ov.w, wv.w, s);
    }
    lg[b][a] = s;
    __syncthreads();
    if (tid < NA) {   // softmax over b for column a = tid
        float mx = -1e30f;
        #pragma unroll
        for (int bb = 0; bb < BATCH; ++bb) mx = fmaxf(mx, lg[bb][tid]);
        float sum = 0.0f;
        #pragma unroll
        for (int bb = 0; bb < BATCH; ++bb) {
            float e = expf(lg[bb][tid] - mx);
            lg[bb][tid] = e;
            sum += e;
        }
        float inv = 1.0f / sum;
        #pragma unroll
        for (int bb = 0; bb < BATCH; ++bb) lg[bb][tid] *= inv;
    }
    __syncthreads();
    if (tid < 48) {
        int bb = tid / 3, dd = tid - 3 * (tid / 3);
        float ss = 0.0f, cc = 0.0f;
        #pragma unroll
        for (int aa = 0; aa < NA; ++aa) {
            float p = lg[bb][aa];
            ss = fmaf(p, sal[aa][dd], ss);
            cc = fmaf(p, cal[aa][dd], cc);
        }
        dih[((size_t)t * BATCH + bb) * 3 + dd] = atan2f(ss, cc);
    }
}

// ---------------------------------------------------------------------------
// K5: sequential NeRF chain. 1 block, lane b < 16 walks its batch serially.
// ---------------------------------------------------------------------------
__global__ void nerf_kernel(const float* __restrict__ dih, float* __restrict__ out) {
    const int b = threadIdx.x;
    if (b >= BATCH) return;
    const float BL0 = 145.801f, BL1 = 152.326f, BL2 = 132.868f;
    const float BA0 = 2.124f,   BA1 = 1.941f,   BA2 = 2.028f;
    const float rr[3] = {BL0, BL1, BL2};
    const float st3[3] = {sinf(BA0), sinf(BA1), sinf(BA2)};
    const float ct3[3] = {cosf(BA0), cosf(BA1), cosf(BA2)};
    float ax = 0.f, ay = 0.f, az = 0.f;
    float bx = BL0, by = 0.f, bz = 0.f;
    float ang = 3.14159265358979323846f - BA0;
    float cx = bx + BL1 * cosf(ang), cy = BL1 * sinf(ang), cz = 0.f;
    for (int l = 0; l < L_SEQ; ++l) {
        #pragma unroll
        for (int d = 0; d < 3; ++d) {
            const int s = l * 3 + d;
            const float r = rr[d], st = st3[d], ct = ct3[d];
            float ph = dih[((size_t)l * BATCH + b) * 3 + d];
            float sp, cp;
            __sincosf(ph, &sp, &cp);
            float d2x = -r * ct, d2y = r * st * cp, d2z = r * st * sp;
            float bcx = cx - bx, bcy = cy - by, bcz = cz - bz;
            float inv = 1.0f / (sqrtf(bcx * bcx + bcy * bcy + bcz * bcz) + 1e-8f);
            bcx *= inv; bcy *= inv; bcz *= inv;
            float abx = bx - ax, aby = by - ay, abz = bz - az;
            float nx = aby * bcz - abz * bcy;
            float ny = abz * bcx - abx * bcz;
            float nz = abx * bcy - aby * bcx;
            inv = 1.0f / (sqrtf(nx * nx + ny * ny + nz * nz) + 1e-8f);
            nx *= inv; ny *= inv; nz *= inv;
            float m1x = ny * bcz - nz * bcy;
            float m1y = nz * bcx - nx * bcz;
            float m1z = nx * bcy - ny * bcx;
            float dx = bcx * d2x + m1x * d2y + nx * d2z + cx;
            float dy = bcy * d2x + m1y * d2y + ny * d2z + cy;
            float dz = bcz * d2x + m1z * d2y + nz * d2z + cz;
            size_t o = ((size_t)s * BATCH + b) * 3;
            out[o + 0] = dx; out[o + 1] = dy; out[o + 2] = dz;
            ax = bx; ay = by; az = bz;
            bx = cx; by = cy; bz = cz;
            cx = dx; cy = dy; cz = dz;
        }
    }
}

// ---------------------------------------------------------------------------
extern "C" void kernel_launch(void* const* d_in, const int* in_sizes, int n_in,
                              void* d_out, int out_size, void* d_ws, size_t ws_size,
                              hipStream_t stream) {
    (void)in_sizes; (void)n_in; (void)out_size; (void)ws_size;
    const float* x        = (const float*)d_in[0];
    const float* W_ih_l0f = (const float*)d_in[1];
    const float* W_hh_l0f = (const float*)d_in[2];
    const float* b_ih_l0f = (const float*)d_in[3];
    const float* b_hh_l0f = (const float*)d_in[4];
    const float* W_ih_l0b = (const float*)d_in[5];
    const float* W_hh_l0b = (const float*)d_in[6];
    const float* b_ih_l0b = (const float*)d_in[7];
    const float* b_hh_l0b = (const float*)d_in[8];
    const float* W_ih_l1f = (const float*)d_in[9];
    const float* W_hh_l1f = (const float*)d_in[10];
    const float* b_ih_l1f = (const float*)d_in[11];
    const float* b_hh_l1f = (const float*)d_in[12];
    const float* W_ih_l1b = (const float*)d_in[13];
    const float* W_hh_l1b = (const float*)d_in[14];
    const float* b_ih_l1b = (const float*)d_in[15];
    const float* b_hh_l1b = (const float*)d_in[16];
    const float* W_lin    = (const float*)d_in[17];
    const float* b_lin    = (const float*)d_in[18];
    const float* alphabet = (const float*)d_in[19];

    float* ws  = (float*)d_ws;
    float* bufA = ws + OFF_A;
    float* bufB = ws + OFF_B;
    float* h12  = ws + OFF_H;    // h1, then reused as h2
    float* dih  = ws + OFF_DIH;
    float* hst  = ws + OFF_HST;
    int*   bar  = (int*)(ws + OFF_BAR);

    // 0. zero barrier state (ws is re-poisoned before every launch)
    hipLaunchKernelGGL(init_bar_kernel, dim3(1), dim3(128), 0, stream, bar);

    // 1. layer-0 pre-activations (both dirs)
    hipLaunchKernelGGL(pre0_kernel, dim3(13, L_SEQ * BATCH, 2), dim3(256), 0, stream,
                       x, W_ih_l0f, b_ih_l0f, b_hh_l0f,
                       W_ih_l0b, b_ih_l0b, b_hh_l0b, bufA, bufB);

    // 2. layer-0 recurrence -> h1 (cooperative launch for co-residency;
    //    sync via custom per-direction barrier)
    {
        const float* a0 = bufA; const float* a1 = bufB;
        const float* a2 = W_hh_l0f; const float* a3 = W_hh_l0b;
        float* a4 = h12; float* a5 = hst; int* a6 = bar;
        void* args[] = {&a0, &a1, &a2, &a3, &a4, &a5, &a6};
        hipLaunchCooperativeKernel((const void*)recur_kernel, dim3(200), dim3(256),
                                   args, 0, stream);
    }

    // 3. layer-1 pre-activations: big fp32 GEMM, overwrites bufA/bufB
    hipLaunchKernelGGL(gemm_pre1_kernel, dim3(G4 / 128, (L_SEQ * BATCH) / 128, 2),
                       dim3(256), 0, stream,
                       h12, W_ih_l1f, b_ih_l1f, b_hh_l1f,
                       W_ih_l1b, b_ih_l1b, b_hh_l1b, bufA, bufB);

    // 4. layer-1 recurrence -> h2 (aliases h1)
    {
        const float* a0 = bufA; const float* a1 = bufB;
        const float* a2 = W_hh_l1f; const float* a3 = W_hh_l1b;
        float* a4 = h12; float* a5 = hst; int* a6 = bar;
        void* args[] = {&a0, &a1, &a2, &a3, &a4, &a5, &a6};
        hipLaunchCooperativeKernel((const void*)recur_kernel, dim3(200), dim3(256),
                                   args, 0, stream);
    }

    // 5. head: linear + softmax(dim=batch) + dihedrals
    hipLaunchKernelGGL(head_kernel, dim3(L_SEQ), dim3(320), 0, stream,
                       h12, W_lin, b_lin, alphabet, dih);

    // 6. sequential NeRF extension
    hipLaunchKernelGGL(nerf_kernel, dim3(1), dim3(64), 0, stream,
                       dih, (float*)d_out);
}

// Round 4
// 22286.409 us; speedup vs baseline: 2.7921x; 1.2906x over previous
//
#include <hip/hip_runtime.h>
#include <math.h>

#define L_SEQ 512
#define BATCH 16
#define D_IN  41
#define HD    800
#define G4    3200   // 4*H
#define A2H   1600   // 2*H
#define NA    20

// workspace layout (float offsets). Peak ~250.4 MiB.
#define OFF_A   ((size_t)0)                                   // pre dir-f: [512][16][3200]
#define OFF_B   (OFF_A + (size_t)L_SEQ * BATCH * G4)          // pre dir-b
#define OFF_H   (OFF_B + (size_t)L_SEQ * BATCH * G4)          // h1 / h2: [512][16][1600]
#define OFF_DIH (OFF_H + (size_t)L_SEQ * BATCH * A2H)         // [512][16][3]
#define OFF_HST (OFF_DIH + (size_t)L_SEQ * BATCH * 3)         // h state [2 dir][2 buf][800][16]
#define OFF_BAR (OFF_HST + (size_t)2 * 2 * HD * BATCH)        // barrier: 128 ints

static __device__ __forceinline__ float sigf(float x) {
    return 1.0f / (1.0f + __expf(-x));
}

// ---------------------------------------------------------------------------
// Monotonic-counter barrier with RELAXED agent atomics only (sc1 / MALL ops,
// no buffer_wbl2 / buffer_inv cache maintenance). Correctness: each wave's
// prior sc1 h-stores are drained by the s_waitcnt vmcnt(0) that
// __syncthreads() emits before s_barrier; thread0's fetch_add therefore
// reaches the MALL after them. A spinner that observes cnt >= target issues
// its subsequent h-loads (program-order dependent) after all 100 increments
// -- hence after all h-stores -- have completed at the MALL.
// ---------------------------------------------------------------------------
static __device__ __forceinline__ void mbar(int* cnt, int target) {
    __syncthreads();
    if (threadIdx.x == 0) {
        asm volatile("" ::: "memory");
        __hip_atomic_fetch_add(cnt, 1, __ATOMIC_RELAXED, __HIP_MEMORY_SCOPE_AGENT);
        while (__hip_atomic_load(cnt, __ATOMIC_RELAXED, __HIP_MEMORY_SCOPE_AGENT) < target)
            __builtin_amdgcn_s_sleep(2);
        asm volatile("" ::: "memory");
    }
    __syncthreads();
}

__global__ void init_bar_kernel(int* bar) {
    bar[threadIdx.x] = 0;   // layer0: cnt@[0](dirF), [32](dirB); layer1: [64],[96]
}

// ---------------------------------------------------------------------------
// K1: pre0[dir][t*16+b][g] = x[b][t][:41] . W_ih0[dir][g][:41] + b_ih + b_hh
// ---------------------------------------------------------------------------
__global__ void pre0_kernel(const float* __restrict__ x,
                            const float* __restrict__ Wf, const float* __restrict__ bif,
                            const float* __restrict__ bhf,
                            const float* __restrict__ Wb, const float* __restrict__ bib,
                            const float* __restrict__ bhb,
                            float* __restrict__ outF, float* __restrict__ outB) {
    int g = blockIdx.x * 256 + threadIdx.x;
    if (g >= G4) return;
    int m = blockIdx.y;           // m = t*16 + b
    int dir = blockIdx.z;
    int b = m & 15, t = m >> 4;
    const float* W  = dir ? Wb  : Wf;
    const float* bi = dir ? bib : bif;
    const float* bh = dir ? bhb : bhf;
    float acc = bi[g] + bh[g];
    const float* xr = x + ((size_t)b * L_SEQ + t) * D_IN;   // x is [B][L][D]
    const float* wr = W + (size_t)g * D_IN;
    #pragma unroll
    for (int d = 0; d < D_IN; ++d) acc = fmaf(xr[d], wr[d], acc);
    (dir ? outB : outF)[(size_t)m * G4 + g] = acc;
}

// ---------------------------------------------------------------------------
// K2: bidirectional LSTM recurrence. 200 blocks x 256 threads (cooperative
// for co-residency): block = (dir = bid&1, wg = bid>>1); wg owns 8 hidden
// units (32 gate rows), W_hh slice persistent in VGPRs (w[4][25]/lane).
// All cross-block h traffic via relaxed agent (sc1/MALL) atomics.
// ---------------------------------------------------------------------------
__launch_bounds__(256, 1)
__global__ void recur_kernel(const float* __restrict__ preF, const float* __restrict__ preB,
                             const float* __restrict__ WhhF, const float* __restrict__ WhhB,
                             float* __restrict__ hout, float* __restrict__ hstate,
                             int* __restrict__ bar) {
    __shared__ float uni[13600];   // union: h stage (800*17) / reduce scratch (16*16*35)
    __shared__ float gates[512];   // [gate][jj][b]
    const int tid = threadIdx.x;
    const int dir = blockIdx.x & 1;
    const int wg  = blockIdx.x >> 1;          // 0..99
    const int j0  = wg * 8;
    const float* pre = dir ? preB : preF;     // [512*16][3200]
    const float* Whh = dir ? WhhB : WhhF;     // [3200][800]
    float* hstd = hstate + (size_t)dir * 2 * HD * BATCH;
    int* cnt = bar + dir * 32;

    // zero this direction's h-state buffer 1 (read at it=0) via sc1 stores
    for (int i = wg * 256 + tid; i < HD * BATCH; i += 100 * 256)
        __hip_atomic_store(&hstd[HD * BATCH + i], 0.0f,
                           __ATOMIC_RELAXED, __HIP_MEMORY_SCOPE_AGENT);

    // persistent W_hh slice in registers
    const int q = tid >> 5, c = tid & 31;
    float w[4][25];
    #pragma unroll
    for (int gi = 0; gi < 4; ++gi) {
        int rl = q * 4 + gi;                           // 0..31
        int row = (rl >> 3) * HD + j0 + (rl & 7);      // gate*800 + j
        const float* wr = Whh + (size_t)row * HD + c;
        #pragma unroll
        for (int kk = 0; kk < 25; ++kk) w[gi][kk] = wr[kk * 32];
    }
    float cstate = 0.0f;                 // lanes < 128: c for (jj=tid>>4, b=tid&15)
    const int r2p = tid & 15, bp = tid >> 4;

    mbar(cnt, 100);   // zero-fill visible at MALL

    for (int it = 0; it < L_SEQ; ++it) {
        const int t = dir ? (L_SEQ - 1 - it) : it;

        // prefetch this lane's two pre-activation values (plain cached loads)
        float pv[2];
        #pragma unroll
        for (int hh = 0; hh < 2; ++hh) {
            int rl = (r2p >> 1) * 4 + (r2p & 1) + 2 * hh;
            int row = (rl >> 3) * HD + j0 + (rl & 7);
            pv[hh] = pre[((size_t)t * BATCH + bp) * G4 + row];
        }

        // stage h_prev into LDS via 8B sc1 loads, layout [k][b] stride 17
        const unsigned long long* hsrc8 = (const unsigned long long*)
            (hstd + ((it & 1) ^ 1) * (HD * BATCH));
        #pragma unroll
        for (int i = 0; i < 25; ++i) {
            int e8 = tid + i * 256;               // 6400 float2 per step
            union { unsigned long long u; float f[2]; } cv;
            cv.u = __hip_atomic_load(hsrc8 + e8, __ATOMIC_RELAXED,
                                     __HIP_MEMORY_SCOPE_AGENT);
            int e = e8 * 2, k = e >> 4, b = e & 15;
            uni[k * 17 + b]     = cv.f[0];
            uni[k * 17 + b + 1] = cv.f[1];
        }
        __syncthreads();

        // phase A: acc[gi][b] += w[gi][kk] * h[b][c+32kk]
        float acc[4][16];
        #pragma unroll
        for (int gi = 0; gi < 4; ++gi)
            #pragma unroll
            for (int b = 0; b < 16; ++b) acc[gi][b] = 0.0f;
        #pragma unroll
        for (int kk = 0; kk < 25; ++kk) {
            const int kb = (c + kk * 32) * 17;
            float hreg[16];
            #pragma unroll
            for (int b = 0; b < 16; ++b) hreg[b] = uni[kb + b];
            #pragma unroll
            for (int gi = 0; gi < 4; ++gi)
                #pragma unroll
                for (int b = 0; b < 16; ++b)
                    acc[gi][b] = fmaf(w[gi][kk], hreg[b], acc[gi][b]);
        }
        __syncthreads();   // h consumed; reuse uni as reduce scratch

        // phase B: reduce over the 32 k-chunks, two halves to fit LDS
        #pragma unroll
        for (int half = 0; half < 2; ++half) {
            #pragma unroll
            for (int u = 0; u < 2; ++u) {
                const int r2w = q * 2 + u;
                #pragma unroll
                for (int b = 0; b < 16; ++b)
                    uni[(b * 16 + r2w) * 35 + c] = acc[2 * half + u][b];
            }
            __syncthreads();
            {
                float s = pv[half];
                const int base = (bp * 16 + r2p) * 35;
                #pragma unroll
                for (int cc = 0; cc < 32; ++cc) s += uni[base + cc];
                int rl = (r2p >> 1) * 4 + (r2p & 1) + 2 * half;
                int gate = rl >> 3, jj = rl & 7;
                gates[gate * 128 + jj * 16 + bp] = s;
            }
            __syncthreads();
        }

        // pointwise LSTM update; h to MALL (sc1) + layer output (plain)
        if (tid < 128) {
            const int jj = tid >> 4, b = tid & 15;
            float ig = gates[0 * 128 + jj * 16 + b];
            float fg = gates[1 * 128 + jj * 16 + b];
            float gg = gates[2 * 128 + jj * 16 + b];
            float og = gates[3 * 128 + jj * 16 + b];
            float cn = sigf(fg) * cstate + sigf(ig) * tanhf(gg);
            cstate = cn;
            float hn = sigf(og) * tanhf(cn);
            __hip_atomic_store(&hstd[(it & 1) * (HD * BATCH) + (j0 + jj) * 16 + b],
                               hn, __ATOMIC_RELAXED, __HIP_MEMORY_SCOPE_AGENT);
            hout[((size_t)t * BATCH + b) * A2H + dir * HD + j0 + jj] = hn;
        }
        mbar(cnt, 100 * (it + 2));
    }
}

// ---------------------------------------------------------------------------
// K3: pre1[dir][m][n] = h1[m][:1600] . W_ih1[dir][n][:1600] + b_ih + b_hh
// 128x128 tile, 256 threads, 8x8 micro-tile, BK=16. grid (25, 64, 2).
// ---------------------------------------------------------------------------
__launch_bounds__(256)
__global__ void gemm_pre1_kernel(const float* __restrict__ Ah,
                                 const float* __restrict__ WF, const float* __restrict__ biF,
                                 const float* __restrict__ bhF,
                                 const float* __restrict__ WB, const float* __restrict__ biB,
                                 const float* __restrict__ bhB,
                                 float* __restrict__ CF, float* __restrict__ CB) {
    __shared__ float As[16][132];
    __shared__ float Bs[16][132];
    const int dir = blockIdx.z;
    const float* Bw = dir ? WB : WF;
    const float* bi = dir ? biB : biF;
    const float* bh = dir ? bhB : bhF;
    float* C = dir ? CB : CF;
    const int n0 = blockIdx.x * 128;
    const int m0 = blockIdx.y * 128;
    const int tid = threadIdx.x;
    const int mt = tid >> 4, nt = tid & 15;
    const int r = tid >> 2, kq = tid & 3;

    float acc[8][8];
    #pragma unroll
    for (int i = 0; i < 8; ++i)
        #pragma unroll
        for (int j = 0; j < 8; ++j) acc[i][j] = 0.0f;

    for (int k0 = 0; k0 < A2H; k0 += 16) {
        float4 a0 = *(const float4*)(Ah + (size_t)(m0 + r) * A2H + k0 + kq * 4);
        float4 a1 = *(const float4*)(Ah + (size_t)(m0 + r + 64) * A2H + k0 + kq * 4);
        float4 b0 = *(const float4*)(Bw + (size_t)(n0 + r) * A2H + k0 + kq * 4);
        float4 b1 = *(const float4*)(Bw + (size_t)(n0 + r + 64) * A2H + k0 + kq * 4);
        __syncthreads();
        As[kq * 4 + 0][r] = a0.x;  As[kq * 4 + 1][r] = a0.y;
        As[kq * 4 + 2][r] = a0.z;  As[kq * 4 + 3][r] = a0.w;
        As[kq * 4 + 0][r + 64] = a1.x;  As[kq * 4 + 1][r + 64] = a1.y;
        As[kq * 4 + 2][r + 64] = a1.z;  As[kq * 4 + 3][r + 64] = a1.w;
        Bs[kq * 4 + 0][r] = b0.x;  Bs[kq * 4 + 1][r] = b0.y;
        Bs[kq * 4 + 2][r] = b0.z;  Bs[kq * 4 + 3][r] = b0.w;
        Bs[kq * 4 + 0][r + 64] = b1.x;  Bs[kq * 4 + 1][r + 64] = b1.y;
        Bs[kq * 4 + 2][r + 64] = b1.z;  Bs[kq * 4 + 3][r + 64] = b1.w;
        __syncthreads();
        #pragma unroll
        for (int kk = 0; kk < 16; ++kk) {
            float av[8], bv[8];
            #pragma unroll
            for (int j = 0; j < 8; ++j) av[j] = As[kk][mt * 8 + j];
            #pragma unroll
            for (int j = 0; j < 8; ++j) bv[j] = Bs[kk][nt * 8 + j];
            #pragma unroll
            for (int i = 0; i < 8; ++i)
                #pragma unroll
                for (int j = 0; j < 8; ++j)
                    acc[i][j] = fmaf(av[i], bv[j], acc[i][j]);
        }
    }
    float bias[8];
    #pragma unroll
    for (int j = 0; j < 8; ++j) { int n = n0 + nt * 8 + j; bias[j] = bi[n] + bh[n]; }
    #pragma unroll
    for (int i = 0; i < 8; ++i) {
        size_t base = (size_t)(m0 + mt * 8 + i) * G4 + n0 + nt * 8;
        #pragma unroll
        for (int j = 0; j < 8; ++j) C[base + j] = acc[i][j] + bias[j];
    }
}

// ---------------------------------------------------------------------------
// K4: linear head + softmax over BATCH dim + dihedrals. One block per t.
// ---------------------------------------------------------------------------
__global__ void head_kernel(const float* __restrict__ out2,   // [8192][1600]
                            const float* __restrict__ Wlin,   // [20][1600]
                            const float* __restrict__ blin,   // [20]
                            const float* __restrict__ alphabet, // [20][3]
                            float* __restrict__ dih) {        // [512][16][3]
    __shared__ float lg[16][21];
    __shared__ float sal[20][3], cal[20][3];
    const int t = blockIdx.x;
    const int tid = threadIdx.x;
    if (tid < 60) {
        int a = tid / 3, d = tid - 3 * (tid / 3);
        float v = alphabet[a * 3 + d];
        sal[a][d] = sinf(v);
        cal[a][d] = cosf(v);
    }
    const int b = tid / 20, a = tid - 20 * (tid / 20);
    const float* orow = out2 + ((size_t)t * BATCH + b) * A2H;
    const float* wrow = Wlin + (size_t)a * A2H;
    float s = blin[a];
    for (int k = 0; k < A2H; k += 4) {
        float4 ov = *(const float4*)(orow + k);
        float4 wv = *(const float4*)(wrow + k);
        s = fmaf(ov.x, wv.x, s);
        s = fmaf(ov.y, wv.y, s);
        s = fmaf(ov.z, wv.z, s);
        s = fmaf(ov.w, wv.w, s);
    }
    lg[b][a] = s;
    __syncthreads();
    if (tid < NA) {   // softmax over b for column a = tid
        float mx = -1e30f;
        #pragma unroll
        for (int bb = 0; bb < BATCH; ++bb) mx = fmaxf(mx, lg[bb][tid]);
        float sum = 0.0f;
        #pragma unroll
        for (int bb = 0; bb < BATCH; ++bb) {
            float e = expf(lg[bb][tid] - mx);
            lg[bb][tid] = e;
            sum += e;
        }
        float inv = 1.0f / sum;
        #pragma unroll
        for (int bb = 0; bb < BATCH; ++bb) lg[bb][tid] *= inv;
    }
    __syncthreads();
    if (tid < 48) {
        int bb = tid / 3, dd = tid - 3 * (tid / 3);
        float ss = 0.0f, cc = 0.0f;
        #pragma unroll
        for (int aa = 0; aa < NA; ++aa) {
            float p = lg[bb][aa];
            ss = fmaf(p, sal[aa][dd], ss);
            cc = fmaf(p, cal[aa][dd], cc);
        }
        dih[((size_t)t * BATCH + bb) * 3 + dd] = atan2f(ss, cc);
    }
}

// ---------------------------------------------------------------------------
// K5: sequential NeRF chain. 1 block, lane b < 16 walks its batch serially.
// ---------------------------------------------------------------------------
__global__ void nerf_kernel(const float* __restrict__ dih, float* __restrict__ out) {
    const int b = threadIdx.x;
    if (b >= BATCH) return;
    const float BL0 = 145.801f, BL1 = 152.326f, BL2 = 132.868f;
    const float BA0 = 2.124f,   BA1 = 1.941f,   BA2 = 2.028f;
    const float rr[3] = {BL0, BL1, BL2};
    const float st3[3] = {sinf(BA0), sinf(BA1), sinf(BA2)};
    const float ct3[3] = {cosf(BA0), cosf(BA1), cosf(BA2)};
    float ax = 0.f, ay = 0.f, az = 0.f;
    float bx = BL0, by = 0.f, bz = 0.f;
    float ang = 3.14159265358979323846f - BA0;
    float cx = bx + BL1 * cosf(ang), cy = BL1 * sinf(ang), cz = 0.f;
    for (int l = 0; l < L_SEQ; ++l) {
        #pragma unroll
        for (int d = 0; d < 3; ++d) {
            const int s = l * 3 + d;
            const float r = rr[d], st = st3[d], ct = ct3[d];
            float ph = dih[((size_t)l * BATCH + b) * 3 + d];
            float sp, cp;
            __sincosf(ph, &sp, &cp);
            float d2x = -r * ct, d2y = r * st * cp, d2z = r * st * sp;
            float bcx = cx - bx, bcy = cy - by, bcz = cz - bz;
            float inv = 1.0f / (sqrtf(bcx * bcx + bcy * bcy + bcz * bcz) + 1e-8f);
            bcx *= inv; bcy *= inv; bcz *= inv;
            float abx = bx - ax, aby = by - ay, abz = bz - az;
            float nx = aby * bcz - abz * bcy;
            float ny = abz * bcx - abx * bcz;
            float nz = abx * bcy - aby * bcx;
            inv = 1.0f / (sqrtf(nx * nx + ny * ny + nz * nz) + 1e-8f);
            nx *= inv; ny *= inv; nz *= inv;
            float m1x = ny * bcz - nz * bcy;
            float m1y = nz * bcx - nx * bcz;
            float m1z = nx * bcy - ny * bcx;
            float dx = bcx * d2x + m1x * d2y + nx * d2z + cx;
            float dy = bcy * d2x + m1y * d2y + ny * d2z + cy;
            float dz = bcz * d2x + m1z * d2y + nz * d2z + cz;
            size_t o = ((size_t)s * BATCH + b) * 3;
            out[o + 0] = dx; out[o + 1] = dy; out[o + 2] = dz;
            ax = bx; ay = by; az = bz;
            bx = cx; by = cy; bz = cz;
            cx = dx; cy = dy; cz = dz;
        }
    }
}

// ---------------------------------------------------------------------------
extern "C" void kernel_launch(void* const* d_in, const int* in_sizes, int n_in,
                              void* d_out, int out_size, void* d_ws, size_t ws_size,
                              hipStream_t stream) {
    (void)in_sizes; (void)n_in; (void)out_size; (void)ws_size;
    const float* x        = (const float*)d_in[0];
    const float* W_ih_l0f = (const float*)d_in[1];
    const float* W_hh_l0f = (const float*)d_in[2];
    const float* b_ih_l0f = (const float*)d_in[3];
    const float* b_hh_l0f = (const float*)d_in[4];
    const float* W_ih_l0b = (const float*)d_in[5];
    const float* W_hh_l0b = (const float*)d_in[6];
    const float* b_ih_l0b = (const float*)d_in[7];
    const float* b_hh_l0b = (const float*)d_in[8];
    const float* W_ih_l1f = (const float*)d_in[9];
    const float* W_hh_l1f = (const float*)d_in[10];
    const float* b_ih_l1f = (const float*)d_in[11];
    const float* b_hh_l1f = (const float*)d_in[12];
    const float* W_ih_l1b = (const float*)d_in[13];
    const float* W_hh_l1b = (const float*)d_in[14];
    const float* b_ih_l1b = (const float*)d_in[15];
    const float* b_hh_l1b = (const float*)d_in[16];
    const float* W_lin    = (const float*)d_in[17];
    const float* b_lin    = (const float*)d_in[18];
    const float* alphabet = (const float*)d_in[19];

    float* ws  = (float*)d_ws;
    float* bufA = ws + OFF_A;
    float* bufB = ws + OFF_B;
    float* h12  = ws + OFF_H;    // h1, then reused as h2
    float* dih  = ws + OFF_DIH;
    float* hst  = ws + OFF_HST;
    int*   bar  = (int*)(ws + OFF_BAR);

    // 0. zero barrier counters (ws is re-poisoned before every launch)
    hipLaunchKernelGGL(init_bar_kernel, dim3(1), dim3(128), 0, stream, bar);

    // 1. layer-0 pre-activations (both dirs)
    hipLaunchKernelGGL(pre0_kernel, dim3(13, L_SEQ * BATCH, 2), dim3(256), 0, stream,
                       x, W_ih_l0f, b_ih_l0f, b_hh_l0f,
                       W_ih_l0b, b_ih_l0b, b_hh_l0b, bufA, bufB);

    // 2. layer-0 recurrence -> h1 (cooperative for co-residency; custom
    //    MALL-coherent monotonic barrier, counters bar[0]/bar[32])
    {
        const float* a0 = bufA; const float* a1 = bufB;
        const float* a2 = W_hh_l0f; const float* a3 = W_hh_l0b;
        float* a4 = h12; float* a5 = hst; int* a6 = bar;
        void* args[] = {&a0, &a1, &a2, &a3, &a4, &a5, &a6};
        hipLaunchCooperativeKernel((const void*)recur_kernel, dim3(200), dim3(256),
                                   args, 0, stream);
    }

    // 3. layer-1 pre-activations: big fp32 GEMM, overwrites bufA/bufB
    hipLaunchKernelGGL(gemm_pre1_kernel, dim3(G4 / 128, (L_SEQ * BATCH) / 128, 2),
                       dim3(256), 0, stream,
                       h12, W_ih_l1f, b_ih_l1f, b_hh_l1f,
                       W_ih_l1b, b_ih_l1b, b_hh_l1b, bufA, bufB);

    // 4. layer-1 recurrence -> h2 (aliases h1; fresh counters bar[64]/bar[96])
    {
        const float* a0 = bufA; const float* a1 = bufB;
        const float* a2 = W_hh_l1f; const float* a3 = W_hh_l1b;
        float* a4 = h12; float* a5 = hst; int* a6 = bar + 64;
        void* args[] = {&a0, &a1, &a2, &a3, &a4, &a5, &a6};
        hipLaunchCooperativeKernel((const void*)recur_kernel, dim3(200), dim3(256),
                                   args, 0, stream);
    }

    // 5. head: linear + softmax(dim=batch) + dihedrals
    hipLaunchKernelGGL(head_kernel, dim3(L_SEQ), dim3(320), 0, stream,
                       h12, W_lin, b_lin, alphabet, dih);

    // 6. sequential NeRF extension
    hipLaunchKernelGGL(nerf_kernel, dim3(1), dim3(64), 0, stream,
                       dih, (float*)d_out);
}

// Round 5
// 21992.685 us; speedup vs baseline: 2.8294x; 1.0134x over previous
//
#include <hip/hip_runtime.h>
#include <math.h>

#define L_SEQ 512
#define BATCH 16
#define D_IN  41
#define HD    800
#define G4    3200   // 4*H
#define A2H   1600   // 2*H
#define NA    20

// workspace layout (float offsets). Peak ~250.4 MiB.
#define OFF_A   ((size_t)0)                                   // pre dir-f: [512][16][3200]
#define OFF_B   (OFF_A + (size_t)L_SEQ * BATCH * G4)          // pre dir-b
#define OFF_H   (OFF_B + (size_t)L_SEQ * BATCH * G4)          // h1 / h2: [512][16][1600]
#define OFF_DIH (OFF_H + (size_t)L_SEQ * BATCH * A2H)         // [512][16][3]
#define OFF_HST (OFF_DIH + (size_t)L_SEQ * BATCH * 3)         // h state [2 dir][2 buf][800][16]
#define OFF_BAR (OFF_HST + (size_t)2 * 2 * HD * BATCH)        // flags: 2 launch x 2 dir x 128 x 32 ints
#define FLG_STRIDE 32                                          // 128B per flag line

static __device__ __forceinline__ float sigf(float x) {
    return 1.0f / (1.0f + __expf(-x));
}

// ---------------------------------------------------------------------------
// Distributed flag barrier (per direction, 100 blocks). Arrival: one relaxed
// agent-scope (sc1/MALL) STORE of the monotone step value to this block's
// private 128B line -- no RMW, no serialization. Detection: wave 0's lanes
// poll all 100 flags in parallel (2 coalesced vmem loads) + __all reduce.
// Ordering: each wave's prior sc1 h-stores drain at the vmcnt(0) implied by
// __syncthreads before s_barrier; the flag store follows it; consumers' h
// loads are program-order after the ballot-dependent branch.
// ---------------------------------------------------------------------------
static __device__ __forceinline__ void fbar(int* flg, int wg, int v) {
    __syncthreads();
    if (threadIdx.x == 0)
        __hip_atomic_store(flg + wg * FLG_STRIDE, v,
                           __ATOMIC_RELAXED, __HIP_MEMORY_SCOPE_AGENT);
    if (threadIdx.x < 64) {
        const int i2 = 64 + (int)threadIdx.x;
        for (;;) {
            int v1 = __hip_atomic_load(flg + threadIdx.x * FLG_STRIDE,
                                       __ATOMIC_RELAXED, __HIP_MEMORY_SCOPE_AGENT);
            int v2 = (i2 < 100) ? __hip_atomic_load(flg + i2 * FLG_STRIDE,
                                       __ATOMIC_RELAXED, __HIP_MEMORY_SCOPE_AGENT)
                                : v;
            if (__all(v1 >= v && v2 >= v)) break;
            __builtin_amdgcn_s_sleep(1);
        }
    }
    __syncthreads();
}

__global__ void init_bar_kernel(int* bar) {
    for (int i = blockIdx.x * 256 + threadIdx.x; i < 2 * 2 * 128 * FLG_STRIDE;
         i += gridDim.x * 256)
        bar[i] = 0;
}

// ---------------------------------------------------------------------------
// K1: pre0[dir][t*16+b][g] = x[b][t][:41] . W_ih0[dir][g][:41] + b_ih + b_hh
// ---------------------------------------------------------------------------
__global__ void pre0_kernel(const float* __restrict__ x,
                            const float* __restrict__ Wf, const float* __restrict__ bif,
                            const float* __restrict__ bhf,
                            const float* __restrict__ Wb, const float* __restrict__ bib,
                            const float* __restrict__ bhb,
                            float* __restrict__ outF, float* __restrict__ outB) {
    int g = blockIdx.x * 256 + threadIdx.x;
    if (g >= G4) return;
    int m = blockIdx.y;           // m = t*16 + b
    int dir = blockIdx.z;
    int b = m & 15, t = m >> 4;
    const float* W  = dir ? Wb  : Wf;
    const float* bi = dir ? bib : bif;
    const float* bh = dir ? bhb : bhf;
    float acc = bi[g] + bh[g];
    const float* xr = x + ((size_t)b * L_SEQ + t) * D_IN;   // x is [B][L][D]
    const float* wr = W + (size_t)g * D_IN;
    #pragma unroll
    for (int d = 0; d < D_IN; ++d) acc = fmaf(xr[d], wr[d], acc);
    (dir ? outB : outF)[(size_t)m * G4 + g] = acc;
}

// ---------------------------------------------------------------------------
// K2: bidirectional LSTM recurrence. 200 blocks x 256 threads (cooperative
// for co-residency): block = (dir = bid&1, wg = bid>>1); wg owns 8 hidden
// units (32 gate rows), W_hh slice persistent in VGPRs (w[4][25]/lane).
// Cross-block h traffic via relaxed agent (sc1/MALL) atomics; sync via
// distributed flag barrier (fbar).
// ---------------------------------------------------------------------------
__launch_bounds__(256, 1)
__global__ void recur_kernel(const float* __restrict__ preF, const float* __restrict__ preB,
                             const float* __restrict__ WhhF, const float* __restrict__ WhhB,
                             float* __restrict__ hout, float* __restrict__ hstate,
                             int* __restrict__ bar) {
    __shared__ float uni[13600];   // union: h stage (800*17) / reduce scratch (16*16*35)
    __shared__ float gates[512];   // [gate][jj][b]
    const int tid = threadIdx.x;
    const int dir = blockIdx.x & 1;
    const int wg  = blockIdx.x >> 1;          // 0..99
    const int j0  = wg * 8;
    const float* pre = dir ? preB : preF;     // [512*16][3200]
    const float* Whh = dir ? WhhB : WhhF;     // [3200][800]
    float* hstd = hstate + (size_t)dir * 2 * HD * BATCH;
    int* flg = bar + dir * 128 * FLG_STRIDE;

    // zero this direction's h-state buffer 1 (read at it=0) via sc1 stores
    for (int i = wg * 256 + tid; i < HD * BATCH; i += 100 * 256)
        __hip_atomic_store(&hstd[HD * BATCH + i], 0.0f,
                           __ATOMIC_RELAXED, __HIP_MEMORY_SCOPE_AGENT);

    // persistent W_hh slice in registers
    const int q = tid >> 5, c = tid & 31;
    float w[4][25];
    #pragma unroll
    for (int gi = 0; gi < 4; ++gi) {
        int rl = q * 4 + gi;                           // 0..31
        int row = (rl >> 3) * HD + j0 + (rl & 7);      // gate*800 + j
        const float* wr = Whh + (size_t)row * HD + c;
        #pragma unroll
        for (int kk = 0; kk < 25; ++kk) w[gi][kk] = wr[kk * 32];
    }
    float cstate = 0.0f;                 // lanes < 128: c for (jj=tid>>4, b=tid&15)
    const int r2p = tid & 15, bp = tid >> 4;

    fbar(flg, wg, 1);   // zero-fill visible at MALL

    for (int it = 0; it < L_SEQ; ++it) {
        const int t = dir ? (L_SEQ - 1 - it) : it;

        // prefetch this lane's two pre-activation values (plain cached loads)
        float pv[2];
        #pragma unroll
        for (int hh = 0; hh < 2; ++hh) {
            int rl = (r2p >> 1) * 4 + (r2p & 1) + 2 * hh;
            int row = (rl >> 3) * HD + j0 + (rl & 7);
            pv[hh] = pre[((size_t)t * BATCH + bp) * G4 + row];
        }

        // stage h_prev into LDS via 8B sc1 loads, layout [k][b] stride 17
        const unsigned long long* hsrc8 = (const unsigned long long*)
            (hstd + ((it & 1) ^ 1) * (HD * BATCH));
        #pragma unroll
        for (int i = 0; i < 25; ++i) {
            int e8 = tid + i * 256;               // 6400 float2 per step
            union { unsigned long long u; float f[2]; } cv;
            cv.u = __hip_atomic_load(hsrc8 + e8, __ATOMIC_RELAXED,
                                     __HIP_MEMORY_SCOPE_AGENT);
            int e = e8 * 2, k = e >> 4, b = e & 15;
            uni[k * 17 + b]     = cv.f[0];
            uni[k * 17 + b + 1] = cv.f[1];
        }
        __syncthreads();

        // phase A: acc[gi][b] += w[gi][kk] * h[b][c+32kk]
        float acc[4][16];
        #pragma unroll
        for (int gi = 0; gi < 4; ++gi)
            #pragma unroll
            for (int b = 0; b < 16; ++b) acc[gi][b] = 0.0f;
        #pragma unroll
        for (int kk = 0; kk < 25; ++kk) {
            const int kb = (c + kk * 32) * 17;
            float hreg[16];
            #pragma unroll
            for (int b = 0; b < 16; ++b) hreg[b] = uni[kb + b];
            #pragma unroll
            for (int gi = 0; gi < 4; ++gi)
                #pragma unroll
                for (int b = 0; b < 16; ++b)
                    acc[gi][b] = fmaf(w[gi][kk], hreg[b], acc[gi][b]);
        }
        __syncthreads();   // h consumed; reuse uni as reduce scratch

        // phase B: reduce over the 32 k-chunks, two halves to fit LDS
        #pragma unroll
        for (int half = 0; half < 2; ++half) {
            #pragma unroll
            for (int u = 0; u < 2; ++u) {
                const int r2w = q * 2 + u;
                #pragma unroll
                for (int b = 0; b < 16; ++b)
                    uni[(b * 16 + r2w) * 35 + c] = acc[2 * half + u][b];
            }
            __syncthreads();
            {
                float s = pv[half];
                const int base = (bp * 16 + r2p) * 35;
                #pragma unroll
                for (int cc = 0; cc < 32; ++cc) s += uni[base + cc];
                int rl = (r2p >> 1) * 4 + (r2p & 1) + 2 * half;
                int gate = rl >> 3, jj = rl & 7;
                gates[gate * 128 + jj * 16 + bp] = s;
            }
            __syncthreads();
        }

        // pointwise LSTM update; h to MALL (sc1) + layer output (plain)
        if (tid < 128) {
            const int jj = tid >> 4, b = tid & 15;
            float ig = gates[0 * 128 + jj * 16 + b];
            float fg = gates[1 * 128 + jj * 16 + b];
            float gg = gates[2 * 128 + jj * 16 + b];
            float og = gates[3 * 128 + jj * 16 + b];
            float cn = sigf(fg) * cstate + sigf(ig) * tanhf(gg);
            cstate = cn;
            float hn = sigf(og) * tanhf(cn);
            __hip_atomic_store(&hstd[(it & 1) * (HD * BATCH) + (j0 + jj) * 16 + b],
                               hn, __ATOMIC_RELAXED, __HIP_MEMORY_SCOPE_AGENT);
            hout[((size_t)t * BATCH + b) * A2H + dir * HD + j0 + jj] = hn;
        }
        fbar(flg, wg, it + 2);
    }
}

// ---------------------------------------------------------------------------
// K3: pre1[dir][m][n] = h1[m][:1600] . W_ih1[dir][n][:1600] + b_ih + b_hh
// 128x128 tile, 256 threads, 8x8 micro-tile, BK=16. grid (25, 64, 2).
// ---------------------------------------------------------------------------
__launch_bounds__(256)
__global__ void gemm_pre1_kernel(const float* __restrict__ Ah,
                                 const float* __restrict__ WF, const float* __restrict__ biF,
                                 const float* __restrict__ bhF,
                                 const float* __restrict__ WB, const float* __restrict__ biB,
                                 const float* __restrict__ bhB,
                                 float* __restrict__ CF, float* __restrict__ CB) {
    __shared__ float As[16][132];
    __shared__ float Bs[16][132];
    const int dir = blockIdx.z;
    const float* Bw = dir ? WB : WF;
    const float* bi = dir ? biB : biF;
    const float* bh = dir ? bhB : bhF;
    float* C = dir ? CB : CF;
    const int n0 = blockIdx.x * 128;
    const int m0 = blockIdx.y * 128;
    const int tid = threadIdx.x;
    const int mt = tid >> 4, nt = tid & 15;
    const int r = tid >> 2, kq = tid & 3;

    float acc[8][8];
    #pragma unroll
    for (int i = 0; i < 8; ++i)
        #pragma unroll
        for (int j = 0; j < 8; ++j) acc[i][j] = 0.0f;

    for (int k0 = 0; k0 < A2H; k0 += 16) {
        float4 a0 = *(const float4*)(Ah + (size_t)(m0 + r) * A2H + k0 + kq * 4);
        float4 a1 = *(const float4*)(Ah + (size_t)(m0 + r + 64) * A2H + k0 + kq * 4);
        float4 b0 = *(const float4*)(Bw + (size_t)(n0 + r) * A2H + k0 + kq * 4);
        float4 b1 = *(const float4*)(Bw + (size_t)(n0 + r + 64) * A2H + k0 + kq * 4);
        __syncthreads();
        As[kq * 4 + 0][r] = a0.x;  As[kq * 4 + 1][r] = a0.y;
        As[kq * 4 + 2][r] = a0.z;  As[kq * 4 + 3][r] = a0.w;
        As[kq * 4 + 0][r + 64] = a1.x;  As[kq * 4 + 1][r + 64] = a1.y;
        As[kq * 4 + 2][r + 64] = a1.z;  As[kq * 4 + 3][r + 64] = a1.w;
        Bs[kq * 4 + 0][r] = b0.x;  Bs[kq * 4 + 1][r] = b0.y;
        Bs[kq * 4 + 2][r] = b0.z;  Bs[kq * 4 + 3][r] = b0.w;
        Bs[kq * 4 + 0][r + 64] = b1.x;  Bs[kq * 4 + 1][r + 64] = b1.y;
        Bs[kq * 4 + 2][r + 64] = b1.z;  Bs[kq * 4 + 3][r + 64] = b1.w;
        __syncthreads();
        #pragma unroll
        for (int kk = 0; kk < 16; ++kk) {
            float av[8], bv[8];
            #pragma unroll
            for (int j = 0; j < 8; ++j) av[j] = As[kk][mt * 8 + j];
            #pragma unroll
            for (int j = 0; j < 8; ++j) bv[j] = Bs[kk][nt * 8 + j];
            #pragma unroll
            for (int i = 0; i < 8; ++i)
                #pragma unroll
                for (int j = 0; j < 8; ++j)
                    acc[i][j] = fmaf(av[i], bv[j], acc[i][j]);
        }
    }
    float bias[8];
    #pragma unroll
    for (int j = 0; j < 8; ++j) { int n = n0 + nt * 8 + j; bias[j] = bi[n] + bh[n]; }
    #pragma unroll
    for (int i = 0; i < 8; ++i) {
        size_t base = (size_t)(m0 + mt * 8 + i) * G4 + n0 + nt * 8;
        #pragma unroll
        for (int j = 0; j < 8; ++j) C[base + j] = acc[i][j] + bias[j];
    }
}

// ---------------------------------------------------------------------------
// K4: linear head + softmax over BATCH dim + dihedrals. One block per t.
// ---------------------------------------------------------------------------
__global__ void head_kernel(const float* __restrict__ out2,   // [8192][1600]
                            const float* __restrict__ Wlin,   // [20][1600]
                            const float* __restrict__ blin,   // [20]
                            const float* __restrict__ alphabet, // [20][3]
                            float* __restrict__ dih) {        // [512][16][3]
    __shared__ float lg[16][21];
    __shared__ float sal[20][3], cal[20][3];
    const int t = blockIdx.x;
    const int tid = threadIdx.x;
    if (tid < 60) {
        int a = tid / 3, d = tid - 3 * (tid / 3);
        float v = alphabet[a * 3 + d];
        sal[a][d] = sinf(v);
        cal[a][d] = cosf(v);
    }
    const int b = tid / 20, a = tid - 20 * (tid / 20);
    const float* orow = out2 + ((size_t)t * BATCH + b) * A2H;
    const float* wrow = Wlin + (size_t)a * A2H;
    float s = blin[a];
    for (int k = 0; k < A2H; k += 4) {
        float4 ov = *(const float4*)(orow + k);
        float4 wv = *(const float4*)(wrow + k);
        s = fmaf(ov.x, wv.x, s);
        s = fmaf(ov.y, wv.y, s);
        s = fmaf(ov.z, wv.z, s);
        s = fmaf(ov.w, wv.w, s);
    }
    lg[b][a] = s;
    __syncthreads();
    if (tid < NA) {   // softmax over b for column a = tid
        float mx = -1e30f;
        #pragma unroll
        for (int bb = 0; bb < BATCH; ++bb) mx = fmaxf(mx, lg[bb][tid]);
        float sum = 0.0f;
        #pragma unroll
        for (int bb = 0; bb < BATCH; ++bb) {
            float e = expf(lg[bb][tid] - mx);
            lg[bb][tid] = e;
            sum += e;
        }
        float inv = 1.0f / sum;
        #pragma unroll
        for (int bb = 0; bb < BATCH; ++bb) lg[bb][tid] *= inv;
    }
    __syncthreads();
    if (tid < 48) {
        int bb = tid / 3, dd = tid - 3 * (tid / 3);
        float ss = 0.0f, cc = 0.0f;
        #pragma unroll
        for (int aa = 0; aa < NA; ++aa) {
            float p = lg[bb][aa];
            ss = fmaf(p, sal[aa][dd], ss);
            cc = fmaf(p, cal[aa][dd], cc);
        }
        dih[((size_t)t * BATCH + bb) * 3 + dd] = atan2f(ss, cc);
    }
}

// ---------------------------------------------------------------------------
// K5: sequential NeRF chain. 1 block, lane b < 16 walks its batch serially.
// ---------------------------------------------------------------------------
__global__ void nerf_kernel(const float* __restrict__ dih, float* __restrict__ out) {
    const int b = threadIdx.x;
    if (b >= BATCH) return;
    const float BL0 = 145.801f, BL1 = 152.326f, BL2 = 132.868f;
    const float BA0 = 2.124f,   BA1 = 1.941f,   BA2 = 2.028f;
    const float rr[3] = {BL0, BL1, BL2};
    const float st3[3] = {sinf(BA0), sinf(BA1), sinf(BA2)};
    const float ct3[3] = {cosf(BA0), cosf(BA1), cosf(BA2)};
    float ax = 0.f, ay = 0.f, az = 0.f;
    float bx = BL0, by = 0.f, bz = 0.f;
    float ang = 3.14159265358979323846f - BA0;
    float cx = bx + BL1 * cosf(ang), cy = BL1 * sinf(ang), cz = 0.f;
    for (int l = 0; l < L_SEQ; ++l) {
        #pragma unroll
        for (int d = 0; d < 3; ++d) {
            const int s = l * 3 + d;
            const float r = rr[d], st = st3[d], ct = ct3[d];
            float ph = dih[((size_t)l * BATCH + b) * 3 + d];
            float sp, cp;
            __sincosf(ph, &sp, &cp);
            float d2x = -r * ct, d2y = r * st * cp, d2z = r * st * sp;
            float bcx = cx - bx, bcy = cy - by, bcz = cz - bz;
            float inv = 1.0f / (sqrtf(bcx * bcx + bcy * bcy + bcz * bcz) + 1e-8f);
            bcx *= inv; bcy *= inv; bcz *= inv;
            float abx = bx - ax, aby = by - ay, abz = bz - az;
            float nx = aby * bcz - abz * bcy;
            float ny = abz * bcx - abx * bcz;
            float nz = abx * bcy - aby * bcx;
            inv = 1.0f / (sqrtf(nx * nx + ny * ny + nz * nz) + 1e-8f);
            nx *= inv; ny *= inv; nz *= inv;
            float m1x = ny * bcz - nz * bcy;
            float m1y = nz * bcx - nx * bcz;
            float m1z = nx * bcy - ny * bcx;
            float dx = bcx * d2x + m1x * d2y + nx * d2z + cx;
            float dy = bcy * d2x + m1y * d2y + ny * d2z + cy;
            float dz = bcz * d2x + m1z * d2y + nz * d2z + cz;
            size_t o = ((size_t)s * BATCH + b) * 3;
            out[o + 0] = dx; out[o + 1] = dy; out[o + 2] = dz;
            ax = bx; ay = by; az = bz;
            bx = cx; by = cy; bz = cz;
            cx = dx; cy = dy; cz = dz;
        }
    }
}

// ---------------------------------------------------------------------------
extern "C" void kernel_launch(void* const* d_in, const int* in_sizes, int n_in,
                              void* d_out, int out_size, void* d_ws, size_t ws_size,
                              hipStream_t stream) {
    (void)in_sizes; (void)n_in; (void)out_size; (void)ws_size;
    const float* x        = (const float*)d_in[0];
    const float* W_ih_l0f = (const float*)d_in[1];
    const float* W_hh_l0f = (const float*)d_in[2];
    const float* b_ih_l0f = (const float*)d_in[3];
    const float* b_hh_l0f = (const float*)d_in[4];
    const float* W_ih_l0b = (const float*)d_in[5];
    const float* W_hh_l0b = (const float*)d_in[6];
    const float* b_ih_l0b = (const float*)d_in[7];
    const float* b_hh_l0b = (const float*)d_in[8];
    const float* W_ih_l1f = (const float*)d_in[9];
    const float* W_hh_l1f = (const float*)d_in[10];
    const float* b_ih_l1f = (const float*)d_in[11];
    const float* b_hh_l1f = (const float*)d_in[12];
    const float* W_ih_l1b = (const float*)d_in[13];
    const float* W_hh_l1b = (const float*)d_in[14];
    const float* b_ih_l1b = (const float*)d_in[15];
    const float* b_hh_l1b = (const float*)d_in[16];
    const float* W_lin    = (const float*)d_in[17];
    const float* b_lin    = (const float*)d_in[18];
    const float* alphabet = (const float*)d_in[19];

    float* ws  = (float*)d_ws;
    float* bufA = ws + OFF_A;
    float* bufB = ws + OFF_B;
    float* h12  = ws + OFF_H;    // h1, then reused as h2
    float* dih  = ws + OFF_DIH;
    float* hst  = ws + OFF_HST;
    int*   bar  = (int*)(ws + OFF_BAR);

    // 0. zero flag lines (ws is re-poisoned before every launch)
    hipLaunchKernelGGL(init_bar_kernel, dim3(16), dim3(256), 0, stream, bar);

    // 1. layer-0 pre-activations (both dirs)
    hipLaunchKernelGGL(pre0_kernel, dim3(13, L_SEQ * BATCH, 2), dim3(256), 0, stream,
                       x, W_ih_l0f, b_ih_l0f, b_hh_l0f,
                       W_ih_l0b, b_ih_l0b, b_hh_l0b, bufA, bufB);

    // 2. layer-0 recurrence -> h1 (cooperative for co-residency; distributed
    //    flag barrier in bar[0 .. 2*128*32))
    {
        const float* a0 = bufA; const float* a1 = bufB;
        const float* a2 = W_hh_l0f; const float* a3 = W_hh_l0b;
        float* a4 = h12; float* a5 = hst; int* a6 = bar;
        void* args[] = {&a0, &a1, &a2, &a3, &a4, &a5, &a6};
        hipLaunchCooperativeKernel((const void*)recur_kernel, dim3(200), dim3(256),
                                   args, 0, stream);
    }

    // 3. layer-1 pre-activations: big fp32 GEMM, overwrites bufA/bufB
    hipLaunchKernelGGL(gemm_pre1_kernel, dim3(G4 / 128, (L_SEQ * BATCH) / 128, 2),
                       dim3(256), 0, stream,
                       h12, W_ih_l1f, b_ih_l1f, b_hh_l1f,
                       W_ih_l1b, b_ih_l1b, b_hh_l1b, bufA, bufB);

    // 4. layer-1 recurrence -> h2 (aliases h1; fresh flag area)
    {
        const float* a0 = bufA; const float* a1 = bufB;
        const float* a2 = W_hh_l1f; const float* a3 = W_hh_l1b;
        float* a4 = h12; float* a5 = hst; int* a6 = bar + 2 * 128 * FLG_STRIDE;
        void* args[] = {&a0, &a1, &a2, &a3, &a4, &a5, &a6};
        hipLaunchCooperativeKernel((const void*)recur_kernel, dim3(200), dim3(256),
                                   args, 0, stream);
    }

    // 5. head: linear + softmax(dim=batch) + dihedrals
    hipLaunchKernelGGL(head_kernel, dim3(L_SEQ), dim3(320), 0, stream,
                       h12, W_lin, b_lin, alphabet, dih);

    // 6. sequential NeRF extension
    hipLaunchKernelGGL(nerf_kernel, dim3(1), dim3(64), 0, stream,
                       dih, (float*)d_out);
}

// Round 6
// 17149.281 us; speedup vs baseline: 3.6284x; 1.2824x over previous
//
#include <hip/hip_runtime.h>
#include <math.h>

#define L_SEQ 512
#define BATCH 16
#define D_IN  41
#define HD    800
#define G4    3200   // 4*H
#define A2H   1600   // 2*H
#define NA    20

// workspace layout (float offsets). Peak ~178 MiB.
#define OFF_A   ((size_t)0)                                   // pre dir-f: [512][16][3200]
#define OFF_B   (OFF_A + (size_t)L_SEQ * BATCH * G4)          // pre dir-b
#define OFF_H   (OFF_B + (size_t)L_SEQ * BATCH * G4)          // h1 / h2: [512][16][1600]
#define OFF_DIH (OFF_H + (size_t)L_SEQ * BATCH * A2H)         // [512][16][3]
#define OFF_BAR (OFF_DIH + (size_t)L_SEQ * BATCH * 3)         // flags: 2 launch x 2 dir x 160 x 32 ints
#define FLG_STRIDE 32                                          // 128B per flag line
#define DIR_STRIDE (160 * FLG_STRIDE)                          // per-direction flag region
#define LAUNCH_STRIDE (2 * DIR_STRIDE)

static __device__ __forceinline__ float sigf(float x) {
    return 1.0f / (1.0f + __expf(-x));
}

// ---------------------------------------------------------------------------
// Two-level flag barrier (per direction, 100 blocks).
//  - arrival: one relaxed agent (sc1/MALL) store of the monotone step value
//    to this block's private 128B line (no RMW).
//  - detection: ONLY block wg==0 gathers the 100 flags (wave 0, 2 lines/lane),
//    then publishes a single `done` word; all other blocks poll just that one
//    broadcast line => ~100x less MALL poll traffic than all-blocks-gather.
// Ordering: producers' sc1 h-stores drain at the vmcnt(0) __syncthreads emits
// before s_barrier; flag store follows; detector's done-store is program-order
// after its flag loads returned; consumers' h-loads are control-dependent on
// the done observation. All ops meet at the MALL (coherent point).
// ---------------------------------------------------------------------------
static __device__ __forceinline__ void fbar2(int* flg, int* done, int wg, int v) {
    __syncthreads();
    if (threadIdx.x == 0)
        __hip_atomic_store(flg + wg * FLG_STRIDE, v,
                           __ATOMIC_RELAXED, __HIP_MEMORY_SCOPE_AGENT);
    if (wg == 0) {
        if (threadIdx.x < 64) {
            const int i2 = 64 + (int)threadIdx.x;
            for (;;) {
                int v1 = __hip_atomic_load(flg + (int)threadIdx.x * FLG_STRIDE,
                                           __ATOMIC_RELAXED, __HIP_MEMORY_SCOPE_AGENT);
                int v2 = (i2 < 100) ? __hip_atomic_load(flg + i2 * FLG_STRIDE,
                                           __ATOMIC_RELAXED, __HIP_MEMORY_SCOPE_AGENT)
                                    : v;
                if (__all(v1 >= v && v2 >= v)) break;
                __builtin_amdgcn_s_sleep(1);
            }
            if (threadIdx.x == 0)
                __hip_atomic_store(done, v, __ATOMIC_RELAXED, __HIP_MEMORY_SCOPE_AGENT);
        }
    } else if (threadIdx.x == 0) {
        while (__hip_atomic_load(done, __ATOMIC_RELAXED, __HIP_MEMORY_SCOPE_AGENT) < v)
            __builtin_amdgcn_s_sleep(2);
    }
    __syncthreads();
}

__global__ void init_bar_kernel(int* bar) {
    for (int i = blockIdx.x * 256 + threadIdx.x; i < 2 * LAUNCH_STRIDE;
         i += gridDim.x * 256)
        bar[i] = 0;
}

// ---------------------------------------------------------------------------
// K1: pre0[dir][t*16+b][g] = x[b][t][:41] . W_ih0[dir][g][:41] + b_ih + b_hh
// ---------------------------------------------------------------------------
__global__ void pre0_kernel(const float* __restrict__ x,
                            const float* __restrict__ Wf, const float* __restrict__ bif,
                            const float* __restrict__ bhf,
                            const float* __restrict__ Wb, const float* __restrict__ bib,
                            const float* __restrict__ bhb,
                            float* __restrict__ outF, float* __restrict__ outB) {
    int g = blockIdx.x * 256 + threadIdx.x;
    if (g >= G4) return;
    int m = blockIdx.y;           // m = t*16 + b
    int dir = blockIdx.z;
    int b = m & 15, t = m >> 4;
    const float* W  = dir ? Wb  : Wf;
    const float* bi = dir ? bib : bif;
    const float* bh = dir ? bhb : bhf;
    float acc = bi[g] + bh[g];
    const float* xr = x + ((size_t)b * L_SEQ + t) * D_IN;   // x is [B][L][D]
    const float* wr = W + (size_t)g * D_IN;
    #pragma unroll
    for (int d = 0; d < D_IN; ++d) acc = fmaf(xr[d], wr[d], acc);
    (dir ? outB : outF)[(size_t)m * G4 + g] = acc;
}

// ---------------------------------------------------------------------------
// K2: bidirectional LSTM recurrence. 200 blocks x 256 threads (cooperative
// for co-residency): block = (dir = bid&1, wg = bid>>1); wg owns 8 hidden
// units (32 gate rows), W_hh slice persistent in VGPRs (w[4][25]/lane).
// h exchange: producers sc1-store h into hout[t] (MALL); consumers stage
// h_{t-1} from hout[t_prev] with PIPELINED raw sc0/sc1 dwordx4 loads (one
// asm block, single vmcnt wait). Sync via two-level flag barrier.
// ---------------------------------------------------------------------------
__launch_bounds__(256, 1)
__global__ void recur_kernel(const float* __restrict__ preF, const float* __restrict__ preB,
                             const float* __restrict__ WhhF, const float* __restrict__ WhhB,
                             float* __restrict__ hout, int* __restrict__ bar) {
    __shared__ float uni[13600];   // union: h stage (800*17) / reduce scratch (16*16*35)
    __shared__ float gates[512];   // [gate][jj][b]
    const int tid = threadIdx.x;
    const int dir = blockIdx.x & 1;
    const int wg  = blockIdx.x >> 1;          // 0..99
    const int j0  = wg * 8;
    const float* pre = dir ? preB : preF;     // [512*16][3200]
    const float* Whh = dir ? WhhB : WhhF;     // [3200][800]
    int* flg  = bar + dir * DIR_STRIDE;
    int* done = flg + 128 * FLG_STRIDE;

    // persistent W_hh slice in registers
    const int q = tid >> 5, c = tid & 31;
    float w[4][25];
    #pragma unroll
    for (int gi = 0; gi < 4; ++gi) {
        int rl = q * 4 + gi;                           // 0..31
        int row = (rl >> 3) * HD + j0 + (rl & 7);      // gate*800 + j
        const float* wr = Whh + (size_t)row * HD + c;
        #pragma unroll
        for (int kk = 0; kk < 25; ++kk) w[gi][kk] = wr[kk * 32];
    }
    float cstate = 0.0f;                 // lanes < 128: c for (jj=tid>>4, b=tid&15)
    const int r2p = tid & 15, bp = tid >> 4;

    // staging index precompute (loop-invariant): 12 float4 + 1 float2 per thread
    int ofs[13], lds[13];
    #pragma unroll
    for (int i = 0; i < 12; ++i) {
        int g = tid * 4 + i * 1024;    // 800 % 4 == 0 -> float4 never crosses a b-row
        int b = g / 800;
        int k = g - 800 * b;
        ofs[i] = 4 * (b * A2H + k);
        lds[i] = k * 17 + b;
    }
    {
        int g = 12288 + tid * 2;
        int b = g / 800;
        int k = g - 800 * b;
        ofs[12] = 4 * (b * A2H + k);
        lds[12] = k * 17 + b;
    }

    for (int it = 0; it < L_SEQ; ++it) {
        const int t = dir ? (L_SEQ - 1 - it) : it;

        // prefetch this lane's two pre-activation values (plain cached loads)
        float pv[2];
        #pragma unroll
        for (int hh = 0; hh < 2; ++hh) {
            int rl = (r2p >> 1) * 4 + (r2p & 1) + 2 * hh;
            int row = (rl >> 3) * HD + j0 + (rl & 7);
            pv[hh] = pre[((size_t)t * BATCH + bp) * G4 + row];
        }

        if (it == 0) {
            // h_{-1} = 0: local LDS zero-fill, no global traffic
            for (int i = tid; i < 13600; i += 256) uni[i] = 0.0f;
        } else {
            const int tprev = dir ? (L_SEQ - it) : (it - 1);
            const float* hsrc = hout + ((size_t)tprev * BATCH) * A2H + dir * HD;
            float4 rr[12];
            float2 r12;
            asm volatile(
                "global_load_dwordx4 %0, %13, %26 sc0 sc1\n\t"
                "global_load_dwordx4 %1, %14, %26 sc0 sc1\n\t"
                "global_load_dwordx4 %2, %15, %26 sc0 sc1\n\t"
                "global_load_dwordx4 %3, %16, %26 sc0 sc1\n\t"
                "global_load_dwordx4 %4, %17, %26 sc0 sc1\n\t"
                "global_load_dwordx4 %5, %18, %26 sc0 sc1\n\t"
                "global_load_dwordx4 %6, %19, %26 sc0 sc1\n\t"
                "global_load_dwordx4 %7, %20, %26 sc0 sc1\n\t"
                "global_load_dwordx4 %8, %21, %26 sc0 sc1\n\t"
                "global_load_dwordx4 %9, %22, %26 sc0 sc1\n\t"
                "global_load_dwordx4 %10, %23, %26 sc0 sc1\n\t"
                "global_load_dwordx4 %11, %24, %26 sc0 sc1\n\t"
                "global_load_dwordx2 %12, %25, %26 sc0 sc1\n\t"
                "s_waitcnt vmcnt(0)"
                : "=&v"(rr[0]), "=&v"(rr[1]), "=&v"(rr[2]), "=&v"(rr[3]),
                  "=&v"(rr[4]), "=&v"(rr[5]), "=&v"(rr[6]), "=&v"(rr[7]),
                  "=&v"(rr[8]), "=&v"(rr[9]), "=&v"(rr[10]), "=&v"(rr[11]),
                  "=&v"(r12)
                : "v"(ofs[0]), "v"(ofs[1]), "v"(ofs[2]), "v"(ofs[3]),
                  "v"(ofs[4]), "v"(ofs[5]), "v"(ofs[6]), "v"(ofs[7]),
                  "v"(ofs[8]), "v"(ofs[9]), "v"(ofs[10]), "v"(ofs[11]),
                  "v"(ofs[12]), "s"(hsrc)
                : "memory");
            #pragma unroll
            for (int i = 0; i < 12; ++i) {
                uni[lds[i]]      = rr[i].x;
                uni[lds[i] + 17] = rr[i].y;
                uni[lds[i] + 34] = rr[i].z;
                uni[lds[i] + 51] = rr[i].w;
            }
            uni[lds[12]]      = r12.x;
            uni[lds[12] + 17] = r12.y;
        }
        __syncthreads();

        // phase A: acc[gi][b] += w[gi][kk] * h[b][c+32kk]
        float acc[4][16];
        #pragma unroll
        for (int gi = 0; gi < 4; ++gi)
            #pragma unroll
            for (int b = 0; b < 16; ++b) acc[gi][b] = 0.0f;
        #pragma unroll
        for (int kk = 0; kk < 25; ++kk) {
            const int kb = (c + kk * 32) * 17;
            float hreg[16];
            #pragma unroll
            for (int b = 0; b < 16; ++b) hreg[b] = uni[kb + b];
            #pragma unroll
            for (int gi = 0; gi < 4; ++gi)
                #pragma unroll
                for (int b = 0; b < 16; ++b)
                    acc[gi][b] = fmaf(w[gi][kk], hreg[b], acc[gi][b]);
        }
        __syncthreads();   // h consumed; reuse uni as reduce scratch

        // phase B: reduce over the 32 k-chunks, two halves to fit LDS
        #pragma unroll
        for (int half = 0; half < 2; ++half) {
            #pragma unroll
            for (int u = 0; u < 2; ++u) {
                const int r2w = q * 2 + u;
                #pragma unroll
                for (int b = 0; b < 16; ++b)
                    uni[(b * 16 + r2w) * 35 + c] = acc[2 * half + u][b];
            }
            __syncthreads();
            {
                float s = pv[half];
                const int base = (bp * 16 + r2p) * 35;
                #pragma unroll
                for (int cc = 0; cc < 32; ++cc) s += uni[base + cc];
                int rl = (r2p >> 1) * 4 + (r2p & 1) + 2 * half;
                int gate = rl >> 3, jj = rl & 7;
                gates[gate * 128 + jj * 16 + bp] = s;
            }
            __syncthreads();
        }

        // pointwise LSTM update; h published to hout[t] at the MALL (sc1)
        if (tid < 128) {
            const int jj = tid >> 4, b = tid & 15;
            float ig = gates[0 * 128 + jj * 16 + b];
            float fg = gates[1 * 128 + jj * 16 + b];
            float gg = gates[2 * 128 + jj * 16 + b];
            float og = gates[3 * 128 + jj * 16 + b];
            float cn = sigf(fg) * cstate + sigf(ig) * tanhf(gg);
            cstate = cn;
            float hn = sigf(og) * tanhf(cn);
            __hip_atomic_store(&hout[((size_t)t * BATCH + b) * A2H + dir * HD + j0 + jj],
                               hn, __ATOMIC_RELAXED, __HIP_MEMORY_SCOPE_AGENT);
        }
        if (it < L_SEQ - 1) fbar2(flg, done, wg, it + 1);
    }
}

// ---------------------------------------------------------------------------
// K3: pre1[dir][m][n] = h1[m][:1600] . W_ih1[dir][n][:1600] + b_ih + b_hh
// 128x128 tile, 256 threads, 8x8 micro-tile, BK=16. grid (25, 64, 2).
// ---------------------------------------------------------------------------
__launch_bounds__(256)
__global__ void gemm_pre1_kernel(const float* __restrict__ Ah,
                                 const float* __restrict__ WF, const float* __restrict__ biF,
                                 const float* __restrict__ bhF,
                                 const float* __restrict__ WB, const float* __restrict__ biB,
                                 const float* __restrict__ bhB,
                                 float* __restrict__ CF, float* __restrict__ CB) {
    __shared__ float As[16][132];
    __shared__ float Bs[16][132];
    const int dir = blockIdx.z;
    const float* Bw = dir ? WB : WF;
    const float* bi = dir ? biB : biF;
    const float* bh = dir ? bhB : bhF;
    float* C = dir ? CB : CF;
    const int n0 = blockIdx.x * 128;
    const int m0 = blockIdx.y * 128;
    const int tid = threadIdx.x;
    const int mt = tid >> 4, nt = tid & 15;
    const int r = tid >> 2, kq = tid & 3;

    float acc[8][8];
    #pragma unroll
    for (int i = 0; i < 8; ++i)
        #pragma unroll
        for (int j = 0; j < 8; ++j) acc[i][j] = 0.0f;

    for (int k0 = 0; k0 < A2H; k0 += 16) {
        float4 a0 = *(const float4*)(Ah + (size_t)(m0 + r) * A2H + k0 + kq * 4);
        float4 a1 = *(const float4*)(Ah + (size_t)(m0 + r + 64) * A2H + k0 + kq * 4);
        float4 b0 = *(const float4*)(Bw + (size_t)(n0 + r) * A2H + k0 + kq * 4);
        float4 b1 = *(const float4*)(Bw + (size_t)(n0 + r + 64) * A2H + k0 + kq * 4);
        __syncthreads();
        As[kq * 4 + 0][r] = a0.x;  As[kq * 4 + 1][r] = a0.y;
        As[kq * 4 + 2][r] = a0.z;  As[kq * 4 + 3][r] = a0.w;
        As[kq * 4 + 0][r + 64] = a1.x;  As[kq * 4 + 1][r + 64] = a1.y;
        As[kq * 4 + 2][r + 64] = a1.z;  As[kq * 4 + 3][r + 64] = a1.w;
        Bs[kq * 4 + 0][r] = b0.x;  Bs[kq * 4 + 1][r] = b0.y;
        Bs[kq * 4 + 2][r] = b0.z;  Bs[kq * 4 + 3][r] = b0.w;
        Bs[kq * 4 + 0][r + 64] = b1.x;  Bs[kq * 4 + 1][r + 64] = b1.y;
        Bs[kq * 4 + 2][r + 64] = b1.z;  Bs[kq * 4 + 3][r + 64] = b1.w;
        __syncthreads();
        #pragma unroll
        for (int kk = 0; kk < 16; ++kk) {
            float av[8], bv[8];
            #pragma unroll
            for (int j = 0; j < 8; ++j) av[j] = As[kk][mt * 8 + j];
            #pragma unroll
            for (int j = 0; j < 8; ++j) bv[j] = Bs[kk][nt * 8 + j];
            #pragma unroll
            for (int i = 0; i < 8; ++i)
                #pragma unroll
                for (int j = 0; j < 8; ++j)
                    acc[i][j] = fmaf(av[i], bv[j], acc[i][j]);
        }
    }
    float bias[8];
    #pragma unroll
    for (int j = 0; j < 8; ++j) { int n = n0 + nt * 8 + j; bias[j] = bi[n] + bh[n]; }
    #pragma unroll
    for (int i = 0; i < 8; ++i) {
        size_t base = (size_t)(m0 + mt * 8 + i) * G4 + n0 + nt * 8;
        #pragma unroll
        for (int j = 0; j < 8; ++j) C[base + j] = acc[i][j] + bias[j];
    }
}

// ---------------------------------------------------------------------------
// K4: linear head + softmax over BATCH dim + dihedrals. One block per t.
// ---------------------------------------------------------------------------
__global__ void head_kernel(const float* __restrict__ out2,   // [8192][1600]
                            const float* __restrict__ Wlin,   // [20][1600]
                            const float* __restrict__ blin,   // [20]
                            const float* __restrict__ alphabet, // [20][3]
                            float* __restrict__ dih) {        // [512][16][3]
    __shared__ float lg[16][21];
    __shared__ float sal[20][3], cal[20][3];
    const int t = blockIdx.x;
    const int tid = threadIdx.x;
    if (tid < 60) {
        int a = tid / 3, d = tid - 3 * (tid / 3);
        float v = alphabet[a * 3 + d];
        sal[a][d] = sinf(v);
        cal[a][d] = cosf(v);
    }
    const int b = tid / 20, a = tid - 20 * (tid / 20);
    const float* orow = out2 + ((size_t)t * BATCH + b) * A2H;
    const float* wrow = Wlin + (size_t)a * A2H;
    float s = blin[a];
    for (int k = 0; k < A2H; k += 4) {
        float4 ov = *(const float4*)(orow + k);
        float4 wv = *(const float4*)(wrow + k);
        s = fmaf(ov.x, wv.x, s);
        s = fmaf(ov.y, wv.y, s);
        s = fmaf(ov.z, wv.z, s);
        s = fmaf(ov.w, wv.w, s);
    }
    lg[b][a] = s;
    __syncthreads();
    if (tid < NA) {   // softmax over b for column a = tid
        float mx = -1e30f;
        #pragma unroll
        for (int bb = 0; bb < BATCH; ++bb) mx = fmaxf(mx, lg[bb][tid]);
        float sum = 0.0f;
        #pragma unroll
        for (int bb = 0; bb < BATCH; ++bb) {
            float e = expf(lg[bb][tid] - mx);
            lg[bb][tid] = e;
            sum += e;
        }
        float inv = 1.0f / sum;
        #pragma unroll
        for (int bb = 0; bb < BATCH; ++bb) lg[bb][tid] *= inv;
    }
    __syncthreads();
    if (tid < 48) {
        int bb = tid / 3, dd = tid - 3 * (tid / 3);
        float ss = 0.0f, cc = 0.0f;
        #pragma unroll
        for (int aa = 0; aa < NA; ++aa) {
            float p = lg[bb][aa];
            ss = fmaf(p, sal[aa][dd], ss);
            cc = fmaf(p, cal[aa][dd], cc);
        }
        dih[((size_t)t * BATCH + bb) * 3 + dd] = atan2f(ss, cc);
    }
}

// ---------------------------------------------------------------------------
// K5: sequential NeRF chain. 1 block, lane b < 16 walks its batch serially.
// ---------------------------------------------------------------------------
__global__ void nerf_kernel(const float* __restrict__ dih, float* __restrict__ out) {
    const int b = threadIdx.x;
    if (b >= BATCH) return;
    const float BL0 = 145.801f, BL1 = 152.326f, BL2 = 132.868f;
    const float BA0 = 2.124f,   BA1 = 1.941f,   BA2 = 2.028f;
    const float rr[3] = {BL0, BL1, BL2};
    const float st3[3] = {sinf(BA0), sinf(BA1), sinf(BA2)};
    const float ct3[3] = {cosf(BA0), cosf(BA1), cosf(BA2)};
    float ax = 0.f, ay = 0.f, az = 0.f;
    float bx = BL0, by = 0.f, bz = 0.f;
    float ang = 3.14159265358979323846f - BA0;
    float cx = bx + BL1 * cosf(ang), cy = BL1 * sinf(ang), cz = 0.f;
    for (int l = 0; l < L_SEQ; ++l) {
        #pragma unroll
        for (int d = 0; d < 3; ++d) {
            const int s = l * 3 + d;
            const float r = rr[d], st = st3[d], ct = ct3[d];
            float ph = dih[((size_t)l * BATCH + b) * 3 + d];
            float sp, cp;
            __sincosf(ph, &sp, &cp);
            float d2x = -r * ct, d2y = r * st * cp, d2z = r * st * sp;
            float bcx = cx - bx, bcy = cy - by, bcz = cz - bz;
            float inv = 1.0f / (sqrtf(bcx * bcx + bcy * bcy + bcz * bcz) + 1e-8f);
            bcx *= inv; bcy *= inv; bcz *= inv;
            float abx = bx - ax, aby = by - ay, abz = bz - az;
            float nx = aby * bcz - abz * bcy;
            float ny = abz * bcx - abx * bcz;
            float nz = abx * bcy - aby * bcx;
            inv = 1.0f / (sqrtf(nx * nx + ny * ny + nz * nz) + 1e-8f);
            nx *= inv; ny *= inv; nz *= inv;
            float m1x = ny * bcz - nz * bcy;
            float m1y = nz * bcx - nx * bcz;
            float m1z = nx * bcy - ny * bcx;
            float dx = bcx * d2x + m1x * d2y + nx * d2z + cx;
            float dy = bcy * d2x + m1y * d2y + ny * d2z + cy;
            float dz = bcz * d2x + m1z * d2y + nz * d2z + cz;
            size_t o = ((size_t)s * BATCH + b) * 3;
            out[o + 0] = dx; out[o + 1] = dy; out[o + 2] = dz;
            ax = bx; ay = by; az = bz;
            bx = cx; by = cy; bz = cz;
            cx = dx; cy = dy; cz = dz;
        }
    }
}

// ---------------------------------------------------------------------------
extern "C" void kernel_launch(void* const* d_in, const int* in_sizes, int n_in,
                              void* d_out, int out_size, void* d_ws, size_t ws_size,
                              hipStream_t stream) {
    (void)in_sizes; (void)n_in; (void)out_size; (void)ws_size;
    const float* x        = (const float*)d_in[0];
    const float* W_ih_l0f = (const float*)d_in[1];
    const float* W_hh_l0f = (const float*)d_in[2];
    const float* b_ih_l0f = (const float*)d_in[3];
    const float* b_hh_l0f = (const float*)d_in[4];
    const float* W_ih_l0b = (const float*)d_in[5];
    const float* W_hh_l0b = (const float*)d_in[6];
    const float* b_ih_l0b = (const float*)d_in[7];
    const float* b_hh_l0b = (const float*)d_in[8];
    const float* W_ih_l1f = (const float*)d_in[9];
    const float* W_hh_l1f = (const float*)d_in[10];
    const float* b_ih_l1f = (const float*)d_in[11];
    const float* b_hh_l1f = (const float*)d_in[12];
    const float* W_ih_l1b = (const float*)d_in[13];
    const float* W_hh_l1b = (const float*)d_in[14];
    const float* b_ih_l1b = (const float*)d_in[15];
    const float* b_hh_l1b = (const float*)d_in[16];
    const float* W_lin    = (const float*)d_in[17];
    const float* b_lin    = (const float*)d_in[18];
    const float* alphabet = (const float*)d_in[19];

    float* ws  = (float*)d_ws;
    float* bufA = ws + OFF_A;
    float* bufB = ws + OFF_B;
    float* h12  = ws + OFF_H;    // h1, then reused as h2 (also the h ring)
    float* dih  = ws + OFF_DIH;
    int*   bar  = (int*)(ws + OFF_BAR);

    // 0. zero flag lines (ws is re-poisoned before every launch)
    hipLaunchKernelGGL(init_bar_kernel, dim3(16), dim3(256), 0, stream, bar);

    // 1. layer-0 pre-activations (both dirs)
    hipLaunchKernelGGL(pre0_kernel, dim3(13, L_SEQ * BATCH, 2), dim3(256), 0, stream,
                       x, W_ih_l0f, b_ih_l0f, b_hh_l0f,
                       W_ih_l0b, b_ih_l0b, b_hh_l0b, bufA, bufB);

    // 2. layer-0 recurrence -> h1 (cooperative for co-residency)
    {
        const float* a0 = bufA; const float* a1 = bufB;
        const float* a2 = W_hh_l0f; const float* a3 = W_hh_l0b;
        float* a4 = h12; int* a5 = bar;
        void* args[] = {&a0, &a1, &a2, &a3, &a4, &a5};
        hipLaunchCooperativeKernel((const void*)recur_kernel, dim3(200), dim3(256),
                                   args, 0, stream);
    }

    // 3. layer-1 pre-activations: big fp32 GEMM, overwrites bufA/bufB
    hipLaunchKernelGGL(gemm_pre1_kernel, dim3(G4 / 128, (L_SEQ * BATCH) / 128, 2),
                       dim3(256), 0, stream,
                       h12, W_ih_l1f, b_ih_l1f, b_hh_l1f,
                       W_ih_l1b, b_ih_l1b, b_hh_l1b, bufA, bufB);

    // 4. layer-1 recurrence -> h2 (aliases h1; fresh flag area)
    {
        const float* a0 = bufA; const float* a1 = bufB;
        const float* a2 = W_hh_l1f; const float* a3 = W_hh_l1b;
        float* a4 = h12; int* a5 = bar + LAUNCH_STRIDE;
        void* args[] = {&a0, &a1, &a2, &a3, &a4, &a5};
        hipLaunchCooperativeKernel((const void*)recur_kernel, dim3(200), dim3(256),
                                   args, 0, stream);
    }

    // 5. head: linear + softmax(dim=batch) + dihedrals
    hipLaunchKernelGGL(head_kernel, dim3(L_SEQ), dim3(320), 0, stream,
                       h12, W_lin, b_lin, alphabet, dih);

    // 6. sequential NeRF extension
    hipLaunchKernelGGL(nerf_kernel, dim3(1), dim3(64), 0, stream,
                       dih, (float*)d_out);
}

// Round 7
// 17128.949 us; speedup vs baseline: 3.6327x; 1.0012x over previous
//
#include <hip/hip_runtime.h>
#include <math.h>

#define L_SEQ 512
#define BATCH 16
#define D_IN  41
#define HD    800
#define G4    3200   // 4*H
#define A2H   1600   // 2*H
#define NA    20

// workspace layout (float offsets). Peak ~178 MiB.
#define OFF_A   ((size_t)0)                                   // pre dir-f: [512][16][3200]
#define OFF_B   (OFF_A + (size_t)L_SEQ * BATCH * G4)          // pre dir-b
#define OFF_H   (OFF_B + (size_t)L_SEQ * BATCH * G4)          // h1 / h2: [512][16][1600]
#define OFF_DIH (OFF_H + (size_t)L_SEQ * BATCH * A2H)         // [512][16][3]
#define OFF_BAR (OFF_DIH + (size_t)L_SEQ * BATCH * 3)         // flag lines
#define FLG_STRIDE 32                                          // 128B per flag line
#define NREP 8                                                 // flag replicas per dir
#define DIR_STRIDE (NREP * 100 * FLG_STRIDE)                   // per-direction flag region
#define LAUNCH_STRIDE (2 * DIR_STRIDE)

static __device__ __forceinline__ float sigf(float x) {
    return 1.0f / (1.0f + __expf(-x));
}

// ---------------------------------------------------------------------------
// Flat replicated-flag barrier (per direction, 100 blocks).
//  - arrival: lanes 0..7 store the monotone step value to 8 REPLICA lines of
//    this block's flag (one wave-store, all replicas land in parallel). No RMW.
//  - detection: wave 0 polls replica set (wg & 7) -- each flag line is polled
//    by only ~25 blocks and all 800 lines are distinct => no shared-line
//    hot-spot, no serial two-level indirection. Tight loop, no s_sleep.
// Ordering: producers' sc1 h-stores drain at the vmcnt(0) __syncthreads emits
// before s_barrier; flag stores are issued after; consumers' staged h-loads
// are control-dependent on the poll observation. All ops meet at the MALL.
// ---------------------------------------------------------------------------
static __device__ __forceinline__ void fbar3(int* flg, int wg, int v) {
    __syncthreads();
    if (threadIdx.x < NREP)
        __hip_atomic_store(flg + ((int)threadIdx.x * 100 + wg) * FLG_STRIDE, v,
                           __ATOMIC_RELAXED, __HIP_MEMORY_SCOPE_AGENT);
    if (threadIdx.x < 64) {
        int* base = flg + ((wg & (NREP - 1)) * 100) * FLG_STRIDE;
        const int i2 = 64 + (int)threadIdx.x;
        for (;;) {
            int v1 = __hip_atomic_load(base + (int)threadIdx.x * FLG_STRIDE,
                                       __ATOMIC_RELAXED, __HIP_MEMORY_SCOPE_AGENT);
            int v2 = (i2 < 100) ? __hip_atomic_load(base + i2 * FLG_STRIDE,
                                       __ATOMIC_RELAXED, __HIP_MEMORY_SCOPE_AGENT)
                                : v;
            if (__all(v1 >= v && v2 >= v)) break;
        }
    }
    __syncthreads();
}

__global__ void init_bar_kernel(int* bar) {
    for (int i = blockIdx.x * 256 + threadIdx.x; i < 2 * LAUNCH_STRIDE;
         i += gridDim.x * 256)
        bar[i] = 0;
}

// ---------------------------------------------------------------------------
// K1: pre0[dir][t*16+b][g] = x[b][t][:41] . W_ih0[dir][g][:41] + b_ih + b_hh
// ---------------------------------------------------------------------------
__global__ void pre0_kernel(const float* __restrict__ x,
                            const float* __restrict__ Wf, const float* __restrict__ bif,
                            const float* __restrict__ bhf,
                            const float* __restrict__ Wb, const float* __restrict__ bib,
                            const float* __restrict__ bhb,
                            float* __restrict__ outF, float* __restrict__ outB) {
    int g = blockIdx.x * 256 + threadIdx.x;
    if (g >= G4) return;
    int m = blockIdx.y;           // m = t*16 + b
    int dir = blockIdx.z;
    int b = m & 15, t = m >> 4;
    const float* W  = dir ? Wb  : Wf;
    const float* bi = dir ? bib : bif;
    const float* bh = dir ? bhb : bhf;
    float acc = bi[g] + bh[g];
    const float* xr = x + ((size_t)b * L_SEQ + t) * D_IN;   // x is [B][L][D]
    const float* wr = W + (size_t)g * D_IN;
    #pragma unroll
    for (int d = 0; d < D_IN; ++d) acc = fmaf(xr[d], wr[d], acc);
    (dir ? outB : outF)[(size_t)m * G4 + g] = acc;
}

// ---------------------------------------------------------------------------
// K2: bidirectional LSTM recurrence. 200 blocks x 256 threads (cooperative
// for co-residency): block = (dir = bid&1, wg = bid>>1); wg owns 8 hidden
// units (32 gate rows), W_hh slice persistent in VGPRs (w[4][25]/lane).
// h exchange: producers sc1-store h into hout[t] (MALL); consumers stage
// h_{t-1} with pipelined raw sc0/sc1 dwordx4 loads (one asm block, single
// vmcnt wait). Sync via flat replicated-flag barrier (fbar3).
// ---------------------------------------------------------------------------
__launch_bounds__(256, 1)
__global__ void recur_kernel(const float* __restrict__ preF, const float* __restrict__ preB,
                             const float* __restrict__ WhhF, const float* __restrict__ WhhB,
                             float* __restrict__ hout, int* __restrict__ bar) {
    __shared__ float uni[13600];   // union: h stage (800*17) / reduce scratch (16*16*35)
    __shared__ float gates[512];   // [gate][jj][b]
    const int tid = threadIdx.x;
    const int dir = blockIdx.x & 1;
    const int wg  = blockIdx.x >> 1;          // 0..99
    const int j0  = wg * 8;
    const float* pre = dir ? preB : preF;     // [512*16][3200]
    const float* Whh = dir ? WhhB : WhhF;     // [3200][800]
    int* flg = bar + dir * DIR_STRIDE;

    // persistent W_hh slice in registers
    const int q = tid >> 5, c = tid & 31;
    float w[4][25];
    #pragma unroll
    for (int gi = 0; gi < 4; ++gi) {
        int rl = q * 4 + gi;                           // 0..31
        int row = (rl >> 3) * HD + j0 + (rl & 7);      // gate*800 + j
        const float* wr = Whh + (size_t)row * HD + c;
        #pragma unroll
        for (int kk = 0; kk < 25; ++kk) w[gi][kk] = wr[kk * 32];
    }
    float cstate = 0.0f;                 // lanes < 128: c for (jj=tid>>4, b=tid&15)
    const int r2p = tid & 15, bp = tid >> 4;

    // staging index precompute (loop-invariant): 12 float4 + 1 float2 per thread
    int ofs[13], lds[13];
    #pragma unroll
    for (int i = 0; i < 12; ++i) {
        int g = tid * 4 + i * 1024;    // 800 % 4 == 0 -> float4 never crosses a b-row
        int b = g / 800;
        int k = g - 800 * b;
        ofs[i] = 4 * (b * A2H + k);
        lds[i] = k * 17 + b;
    }
    {
        int g = 12288 + tid * 2;
        int b = g / 800;
        int k = g - 800 * b;
        ofs[12] = 4 * (b * A2H + k);
        lds[12] = k * 17 + b;
    }

    for (int it = 0; it < L_SEQ; ++it) {
        const int t = dir ? (L_SEQ - 1 - it) : it;

        // prefetch this lane's two pre-activation values (plain cached loads)
        float pv[2];
        #pragma unroll
        for (int hh = 0; hh < 2; ++hh) {
            int rl = (r2p >> 1) * 4 + (r2p & 1) + 2 * hh;
            int row = (rl >> 3) * HD + j0 + (rl & 7);
            pv[hh] = pre[((size_t)t * BATCH + bp) * G4 + row];
        }

        if (it == 0) {
            // h_{-1} = 0: local LDS zero-fill, no global traffic
            for (int i = tid; i < 13600; i += 256) uni[i] = 0.0f;
        } else {
            const int tprev = dir ? (L_SEQ - it) : (it - 1);
            const float* hsrc = hout + ((size_t)tprev * BATCH) * A2H + dir * HD;
            float4 rr[12];
            float2 r12;
            asm volatile(
                "global_load_dwordx4 %0, %13, %26 sc0 sc1\n\t"
                "global_load_dwordx4 %1, %14, %26 sc0 sc1\n\t"
                "global_load_dwordx4 %2, %15, %26 sc0 sc1\n\t"
                "global_load_dwordx4 %3, %16, %26 sc0 sc1\n\t"
                "global_load_dwordx4 %4, %17, %26 sc0 sc1\n\t"
                "global_load_dwordx4 %5, %18, %26 sc0 sc1\n\t"
                "global_load_dwordx4 %6, %19, %26 sc0 sc1\n\t"
                "global_load_dwordx4 %7, %20, %26 sc0 sc1\n\t"
                "global_load_dwordx4 %8, %21, %26 sc0 sc1\n\t"
                "global_load_dwordx4 %9, %22, %26 sc0 sc1\n\t"
                "global_load_dwordx4 %10, %23, %26 sc0 sc1\n\t"
                "global_load_dwordx4 %11, %24, %26 sc0 sc1\n\t"
                "global_load_dwordx2 %12, %25, %26 sc0 sc1\n\t"
                "s_waitcnt vmcnt(0)"
                : "=&v"(rr[0]), "=&v"(rr[1]), "=&v"(rr[2]), "=&v"(rr[3]),
                  "=&v"(rr[4]), "=&v"(rr[5]), "=&v"(rr[6]), "=&v"(rr[7]),
                  "=&v"(rr[8]), "=&v"(rr[9]), "=&v"(rr[10]), "=&v"(rr[11]),
                  "=&v"(r12)
                : "v"(ofs[0]), "v"(ofs[1]), "v"(ofs[2]), "v"(ofs[3]),
                  "v"(ofs[4]), "v"(ofs[5]), "v"(ofs[6]), "v"(ofs[7]),
                  "v"(ofs[8]), "v"(ofs[9]), "v"(ofs[10]), "v"(ofs[11]),
                  "v"(ofs[12]), "s"(hsrc)
                : "memory");
            #pragma unroll
            for (int i = 0; i < 12; ++i) {
                uni[lds[i]]      = rr[i].x;
                uni[lds[i] + 17] = rr[i].y;
                uni[lds[i] + 34] = rr[i].z;
                uni[lds[i] + 51] = rr[i].w;
            }
            uni[lds[12]]      = r12.x;
            uni[lds[12] + 17] = r12.y;
        }
        __syncthreads();

        // phase A: acc[gi][b] += w[gi][kk] * h[b][c+32kk]
        float acc[4][16];
        #pragma unroll
        for (int gi = 0; gi < 4; ++gi)
            #pragma unroll
            for (int b = 0; b < 16; ++b) acc[gi][b] = 0.0f;
        #pragma unroll
        for (int kk = 0; kk < 25; ++kk) {
            const int kb = (c + kk * 32) * 17;
            float hreg[16];
            #pragma unroll
            for (int b = 0; b < 16; ++b) hreg[b] = uni[kb + b];
            #pragma unroll
            for (int gi = 0; gi < 4; ++gi)
                #pragma unroll
                for (int b = 0; b < 16; ++b)
                    acc[gi][b] = fmaf(w[gi][kk], hreg[b], acc[gi][b]);
        }
        __syncthreads();   // h consumed; reuse uni as reduce scratch

        // phase B: reduce over the 32 k-chunks, two halves to fit LDS
        #pragma unroll
        for (int half = 0; half < 2; ++half) {
            #pragma unroll
            for (int u = 0; u < 2; ++u) {
                const int r2w = q * 2 + u;
                #pragma unroll
                for (int b = 0; b < 16; ++b)
                    uni[(b * 16 + r2w) * 35 + c] = acc[2 * half + u][b];
            }
            __syncthreads();
            {
                float s = pv[half];
                const int base = (bp * 16 + r2p) * 35;
                #pragma unroll
                for (int cc = 0; cc < 32; ++cc) s += uni[base + cc];
                int rl = (r2p >> 1) * 4 + (r2p & 1) + 2 * half;
                int gate = rl >> 3, jj = rl & 7;
                gates[gate * 128 + jj * 16 + bp] = s;
            }
            __syncthreads();
        }

        // pointwise LSTM update; h published to hout[t] at the MALL (sc1)
        if (tid < 128) {
            const int jj = tid >> 4, b = tid & 15;
            float ig = gates[0 * 128 + jj * 16 + b];
            float fg = gates[1 * 128 + jj * 16 + b];
            float gg = gates[2 * 128 + jj * 16 + b];
            float og = gates[3 * 128 + jj * 16 + b];
            float cn = sigf(fg) * cstate + sigf(ig) * tanhf(gg);
            cstate = cn;
            float hn = sigf(og) * tanhf(cn);
            __hip_atomic_store(&hout[((size_t)t * BATCH + b) * A2H + dir * HD + j0 + jj],
                               hn, __ATOMIC_RELAXED, __HIP_MEMORY_SCOPE_AGENT);
        }
        if (it < L_SEQ - 1) fbar3(flg, wg, it + 1);
    }
}

// ---------------------------------------------------------------------------
// K3: pre1[dir][m][n] = h1[m][:1600] . W_ih1[dir][n][:1600] + b_ih + b_hh
// 128x128 tile, 256 threads, 8x8 micro-tile, BK=16. grid (25, 64, 2).
// ---------------------------------------------------------------------------
__launch_bounds__(256)
__global__ void gemm_pre1_kernel(const float* __restrict__ Ah,
                                 const float* __restrict__ WF, const float* __restrict__ biF,
                                 const float* __restrict__ bhF,
                                 const float* __restrict__ WB, const float* __restrict__ biB,
                                 const float* __restrict__ bhB,
                                 float* __restrict__ CF, float* __restrict__ CB) {
    __shared__ float As[16][132];
    __shared__ float Bs[16][132];
    const int dir = blockIdx.z;
    const float* Bw = dir ? WB : WF;
    const float* bi = dir ? biB : biF;
    const float* bh = dir ? bhB : bhF;
    float* C = dir ? CB : CF;
    const int n0 = blockIdx.x * 128;
    const int m0 = blockIdx.y * 128;
    const int tid = threadIdx.x;
    const int mt = tid >> 4, nt = tid & 15;
    const int r = tid >> 2, kq = tid & 3;

    float acc[8][8];
    #pragma unroll
    for (int i = 0; i < 8; ++i)
        #pragma unroll
        for (int j = 0; j < 8; ++j) acc[i][j] = 0.0f;

    for (int k0 = 0; k0 < A2H; k0 += 16) {
        float4 a0 = *(const float4*)(Ah + (size_t)(m0 + r) * A2H + k0 + kq * 4);
        float4 a1 = *(const float4*)(Ah + (size_t)(m0 + r + 64) * A2H + k0 + kq * 4);
        float4 b0 = *(const float4*)(Bw + (size_t)(n0 + r) * A2H + k0 + kq * 4);
        float4 b1 = *(const float4*)(Bw + (size_t)(n0 + r + 64) * A2H + k0 + kq * 4);
        __syncthreads();
        As[kq * 4 + 0][r] = a0.x;  As[kq * 4 + 1][r] = a0.y;
        As[kq * 4 + 2][r] = a0.z;  As[kq * 4 + 3][r] = a0.w;
        As[kq * 4 + 0][r + 64] = a1.x;  As[kq * 4 + 1][r + 64] = a1.y;
        As[kq * 4 + 2][r + 64] = a1.z;  As[kq * 4 + 3][r + 64] = a1.w;
        Bs[kq * 4 + 0][r] = b0.x;  Bs[kq * 4 + 1][r] = b0.y;
        Bs[kq * 4 + 2][r] = b0.z;  Bs[kq * 4 + 3][r] = b0.w;
        Bs[kq * 4 + 0][r + 64] = b1.x;  Bs[kq * 4 + 1][r + 64] = b1.y;
        Bs[kq * 4 + 2][r + 64] = b1.z;  Bs[kq * 4 + 3][r + 64] = b1.w;
        __syncthreads();
        #pragma unroll
        for (int kk = 0; kk < 16; ++kk) {
            float av[8], bv[8];
            #pragma unroll
            for (int j = 0; j < 8; ++j) av[j] = As[kk][mt * 8 + j];
            #pragma unroll
            for (int j = 0; j < 8; ++j) bv[j] = Bs[kk][nt * 8 + j];
            #pragma unroll
            for (int i = 0; i < 8; ++i)
                #pragma unroll
                for (int j = 0; j < 8; ++j)
                    acc[i][j] = fmaf(av[i], bv[j], acc[i][j]);
        }
    }
    float bias[8];
    #pragma unroll
    for (int j = 0; j < 8; ++j) { int n = n0 + nt * 8 + j; bias[j] = bi[n] + bh[n]; }
    #pragma unroll
    for (int i = 0; i < 8; ++i) {
        size_t base = (size_t)(m0 + mt * 8 + i) * G4 + n0 + nt * 8;
        #pragma unroll
        for (int j = 0; j < 8; ++j) C[base + j] = acc[i][j] + bias[j];
    }
}

// ---------------------------------------------------------------------------
// K4: linear head + softmax over BATCH dim + dihedrals. One block per t.
// ---------------------------------------------------------------------------
__global__ void head_kernel(const float* __restrict__ out2,   // [8192][1600]
                            const float* __restrict__ Wlin,   // [20][1600]
                            const float* __restrict__ blin,   // [20]
                            const float* __restrict__ alphabet, // [20][3]
                            float* __restrict__ dih) {        // [512][16][3]
    __shared__ float lg[16][21];
    __shared__ float sal[20][3], cal[20][3];
    const int t = blockIdx.x;
    const int tid = threadIdx.x;
    if (tid < 60) {
        int a = tid / 3, d = tid - 3 * (tid / 3);
        float v = alphabet[a * 3 + d];
        sal[a][d] = sinf(v);
        cal[a][d] = cosf(v);
    }
    const int b = tid / 20, a = tid - 20 * (tid / 20);
    const float* orow = out2 + ((size_t)t * BATCH + b) * A2H;
    const float* wrow = Wlin + (size_t)a * A2H;
    float s = blin[a];
    for (int k = 0; k < A2H; k += 4) {
        float4 ov = *(const float4*)(orow + k);
        float4 wv = *(const float4*)(wrow + k);
        s = fmaf(ov.x, wv.x, s);
        s = fmaf(ov.y, wv.y, s);
        s = fmaf(ov.z, wv.z, s);
        s = fmaf(ov.w, wv.w, s);
    }
    lg[b][a] = s;
    __syncthreads();
    if (tid < NA) {   // softmax over b for column a = tid
        float mx = -1e30f;
        #pragma unroll
        for (int bb = 0; bb < BATCH; ++bb) mx = fmaxf(mx, lg[bb][tid]);
        float sum = 0.0f;
        #pragma unroll
        for (int bb = 0; bb < BATCH; ++bb) {
            float e = expf(lg[bb][tid] - mx);
            lg[bb][tid] = e;
            sum += e;
        }
        float inv = 1.0f / sum;
        #pragma unroll
        for (int bb = 0; bb < BATCH; ++bb) lg[bb][tid] *= inv;
    }
    __syncthreads();
    if (tid < 48) {
        int bb = tid / 3, dd = tid - 3 * (tid / 3);
        float ss = 0.0f, cc = 0.0f;
        #pragma unroll
        for (int aa = 0; aa < NA; ++aa) {
            float p = lg[bb][aa];
            ss = fmaf(p, sal[aa][dd], ss);
            cc = fmaf(p, cal[aa][dd], cc);
        }
        dih[((size_t)t * BATCH + bb) * 3 + dd] = atan2f(ss, cc);
    }
}

// ---------------------------------------------------------------------------
// K5: sequential NeRF chain. 1 block, lane b < 16 walks its batch serially.
// ---------------------------------------------------------------------------
__global__ void nerf_kernel(const float* __restrict__ dih, float* __restrict__ out) {
    const int b = threadIdx.x;
    if (b >= BATCH) return;
    const float BL0 = 145.801f, BL1 = 152.326f, BL2 = 132.868f;
    const float BA0 = 2.124f,   BA1 = 1.941f,   BA2 = 2.028f;
    const float rr[3] = {BL0, BL1, BL2};
    const float st3[3] = {sinf(BA0), sinf(BA1), sinf(BA2)};
    const float ct3[3] = {cosf(BA0), cosf(BA1), cosf(BA2)};
    float ax = 0.f, ay = 0.f, az = 0.f;
    float bx = BL0, by = 0.f, bz = 0.f;
    float ang = 3.14159265358979323846f - BA0;
    float cx = bx + BL1 * cosf(ang), cy = BL1 * sinf(ang), cz = 0.f;
    for (int l = 0; l < L_SEQ; ++l) {
        #pragma unroll
        for (int d = 0; d < 3; ++d) {
            const int s = l * 3 + d;
            const float r = rr[d], st = st3[d], ct = ct3[d];
            float ph = dih[((size_t)l * BATCH + b) * 3 + d];
            float sp, cp;
            __sincosf(ph, &sp, &cp);
            float d2x = -r * ct, d2y = r * st * cp, d2z = r * st * sp;
            float bcx = cx - bx, bcy = cy - by, bcz = cz - bz;
            float inv = 1.0f / (sqrtf(bcx * bcx + bcy * bcy + bcz * bcz) + 1e-8f);
            bcx *= inv; bcy *= inv; bcz *= inv;
            float abx = bx - ax, aby = by - ay, abz = bz - az;
            float nx = aby * bcz - abz * bcy;
            float ny = abz * bcx - abx * bcz;
            float nz = abx * bcy - aby * bcx;
            inv = 1.0f / (sqrtf(nx * nx + ny * ny + nz * nz) + 1e-8f);
            nx *= inv; ny *= inv; nz *= inv;
            float m1x = ny * bcz - nz * bcy;
            float m1y = nz * bcx - nx * bcz;
            float m1z = nx * bcy - ny * bcx;
            float dx = bcx * d2x + m1x * d2y + nx * d2z + cx;
            float dy = bcy * d2x + m1y * d2y + ny * d2z + cy;
            float dz = bcz * d2x + m1z * d2y + nz * d2z + cz;
            size_t o = ((size_t)s * BATCH + b) * 3;
            out[o + 0] = dx; out[o + 1] = dy; out[o + 2] = dz;
            ax = bx; ay = by; az = bz;
            bx = cx; by = cy; bz = cz;
            cx = dx; cy = dy; cz = dz;
        }
    }
}

// ---------------------------------------------------------------------------
extern "C" void kernel_launch(void* const* d_in, const int* in_sizes, int n_in,
                              void* d_out, int out_size, void* d_ws, size_t ws_size,
                              hipStream_t stream) {
    (void)in_sizes; (void)n_in; (void)out_size; (void)ws_size;
    const float* x        = (const float*)d_in[0];
    const float* W_ih_l0f = (const float*)d_in[1];
    const float* W_hh_l0f = (const float*)d_in[2];
    const float* b_ih_l0f = (const float*)d_in[3];
    const float* b_hh_l0f = (const float*)d_in[4];
    const float* W_ih_l0b = (const float*)d_in[5];
    const float* W_hh_l0b = (const float*)d_in[6];
    const float* b_ih_l0b = (const float*)d_in[7];
    const float* b_hh_l0b = (const float*)d_in[8];
    const float* W_ih_l1f = (const float*)d_in[9];
    const float* W_hh_l1f = (const float*)d_in[10];
    const float* b_ih_l1f = (const float*)d_in[11];
    const float* b_hh_l1f = (const float*)d_in[12];
    const float* W_ih_l1b = (const float*)d_in[13];
    const float* W_hh_l1b = (const float*)d_in[14];
    const float* b_ih_l1b = (const float*)d_in[15];
    const float* b_hh_l1b = (const float*)d_in[16];
    const float* W_lin    = (const float*)d_in[17];
    const float* b_lin    = (const float*)d_in[18];
    const float* alphabet = (const float*)d_in[19];

    float* ws  = (float*)d_ws;
    float* bufA = ws + OFF_A;
    float* bufB = ws + OFF_B;
    float* h12  = ws + OFF_H;    // h1, then reused as h2 (also the h ring)
    float* dih  = ws + OFF_DIH;
    int*   bar  = (int*)(ws + OFF_BAR);

    // 0. zero flag lines (ws is re-poisoned before every launch)
    hipLaunchKernelGGL(init_bar_kernel, dim3(32), dim3(256), 0, stream, bar);

    // 1. layer-0 pre-activations (both dirs)
    hipLaunchKernelGGL(pre0_kernel, dim3(13, L_SEQ * BATCH, 2), dim3(256), 0, stream,
                       x, W_ih_l0f, b_ih_l0f, b_hh_l0f,
                       W_ih_l0b, b_ih_l0b, b_hh_l0b, bufA, bufB);

    // 2. layer-0 recurrence -> h1 (cooperative for co-residency)
    {
        const float* a0 = bufA; const float* a1 = bufB;
        const float* a2 = W_hh_l0f; const float* a3 = W_hh_l0b;
        float* a4 = h12; int* a5 = bar;
        void* args[] = {&a0, &a1, &a2, &a3, &a4, &a5};
        hipLaunchCooperativeKernel((const void*)recur_kernel, dim3(200), dim3(256),
                                   args, 0, stream);
    }

    // 3. layer-1 pre-activations: big fp32 GEMM, overwrites bufA/bufB
    hipLaunchKernelGGL(gemm_pre1_kernel, dim3(G4 / 128, (L_SEQ * BATCH) / 128, 2),
                       dim3(256), 0, stream,
                       h12, W_ih_l1f, b_ih_l1f, b_hh_l1f,
                       W_ih_l1b, b_ih_l1b, b_hh_l1b, bufA, bufB);

    // 4. layer-1 recurrence -> h2 (aliases h1; fresh flag area)
    {
        const float* a0 = bufA; const float* a1 = bufB;
        const float* a2 = W_hh_l1f; const float* a3 = W_hh_l1b;
        float* a4 = h12; int* a5 = bar + LAUNCH_STRIDE;
        void* args[] = {&a0, &a1, &a2, &a3, &a4, &a5};
        hipLaunchCooperativeKernel((const void*)recur_kernel, dim3(200), dim3(256),
                                   args, 0, stream);
    }

    // 5. head: linear + softmax(dim=batch) + dihedrals
    hipLaunchKernelGGL(head_kernel, dim3(L_SEQ), dim3(320), 0, stream,
                       h12, W_lin, b_lin, alphabet, dih);

    // 6. sequential NeRF extension
    hipLaunchKernelGGL(nerf_kernel, dim3(1), dim3(64), 0, stream,
                       dih, (float*)d_out);
}